// Round 1
// baseline (1983.532 us; speedup 1.0000x reference)
//
#include <hip/hip_runtime.h>

typedef _Float16 f16;
typedef f16  f16x8 __attribute__((ext_vector_type(8)));
typedef f16  f16x4 __attribute__((ext_vector_type(4)));
typedef float f32x4 __attribute__((ext_vector_type(4)));

#define LOAD_LDS16(gp, lp) __builtin_amdgcn_global_load_lds( \
    (const __attribute__((address_space(1))) void*)(gp),     \
    (__attribute__((address_space(3))) void*)(lp), 16, 0, 0)

// ---------------------------------------------------------------- helpers

__global__ __launch_bounds__(256) void castx_kernel(const float* __restrict__ x,
                                                    f16* __restrict__ o) {
  long i = ((long)blockIdx.x * 256 + threadIdx.x) * 4;
  const float4 v = *(const float4*)(x + i);
  f16x4 h; h.x = (f16)v.x; h.y = (f16)v.y; h.z = (f16)v.z; h.w = (f16)v.w;
  *(f16x4*)(o + i) = h;
}

// src [z][R][C] fp32  ->  dst (+z*dbatch) [c][r] fp16 with row stride dld
__global__ __launch_bounds__(256) void transpose_cast(const float* __restrict__ src,
                                                      f16* __restrict__ dst,
                                                      int R, int C, long sbatch,
                                                      long dbatch, int dld) {
  __shared__ float tile[32][33];
  const int zc = blockIdx.x * 32;   // src col tile
  const int zr = blockIdx.y * 32;   // src row tile
  const int z  = blockIdx.z;
  const float* s = src + (long)z * sbatch;
  f16* d = dst + (long)z * dbatch;
  const int tx = threadIdx.x & 31, ty = threadIdx.x >> 5;  // ty in [0,8)
#pragma unroll
  for (int rr = 0; rr < 32; rr += 8)
    tile[ty + rr][tx] = s[(long)(zr + ty + rr) * C + (zc + tx)];
  __syncthreads();
#pragma unroll
  for (int rr = 0; rr < 32; rr += 8)
    d[(long)(zc + ty + rr) * dld + (zr + tx)] = (f16)tile[tx][ty + rr];
}

// gating: logits, top-4-of-12 softmax, dense softmax(6) + entropy. fp32 exact.
__global__ __launch_bounds__(256) void gating_kernel(
    const float* __restrict__ x, const float* __restrict__ gaw,
    const float* __restrict__ gab, const float* __restrict__ ggw,
    const float* __restrict__ ggb, float* __restrict__ wA,
    float* __restrict__ wG, float* __restrict__ ent) {
  const int b = blockIdx.x, t = threadIdx.x;
  const float* xr = x + (long)b * 1024;
  float pa[12], pg[6];
#pragma unroll
  for (int e = 0; e < 12; e++) pa[e] = 0.f;
#pragma unroll
  for (int e = 0; e < 6; e++) pg[e] = 0.f;
  const int i0 = t * 4;
  const float4 xv = *(const float4*)(xr + i0);
  const float xs[4] = {xv.x, xv.y, xv.z, xv.w};
#pragma unroll
  for (int u = 0; u < 4; u++) {
    const float xi = xs[u];
    const float* ga = gaw + (long)(i0 + u) * 12;
    const float* gg = ggw + (long)(i0 + u) * 6;
#pragma unroll
    for (int e = 0; e < 12; e++) pa[e] += xi * ga[e];
#pragma unroll
    for (int e = 0; e < 6; e++) pg[e] += xi * gg[e];
  }
#pragma unroll
  for (int e = 0; e < 12; e++)
    for (int m = 1; m < 64; m <<= 1) pa[e] += __shfl_xor(pa[e], m);
#pragma unroll
  for (int e = 0; e < 6; e++)
    for (int m = 1; m < 64; m <<= 1) pg[e] += __shfl_xor(pg[e], m);
  __shared__ float rw[4][18];
  const int lane = t & 63, wv = t >> 6;
  if (lane == 0) {
#pragma unroll
    for (int e = 0; e < 12; e++) rw[wv][e] = pa[e];
#pragma unroll
    for (int e = 0; e < 6; e++) rw[wv][12 + e] = pg[e];
  }
  __syncthreads();
  if (t == 0) {
    float la[12], lg[6];
#pragma unroll
    for (int e = 0; e < 12; e++)
      la[e] = rw[0][e] + rw[1][e] + rw[2][e] + rw[3][e] + gab[e];
#pragma unroll
    for (int e = 0; e < 6; e++)
      lg[e] = rw[0][12 + e] + rw[1][12 + e] + rw[2][12 + e] + rw[3][12 + e] + ggb[e];
    // top-4 of 12 (first-max on ties, matches lax.top_k)
    unsigned used = 0; float tv[4]; int tix[4];
    for (int k = 0; k < 4; k++) {
      float best = -3.4e38f; int bi = 0;
      for (int e = 0; e < 12; e++)
        if (!((used >> e) & 1u) && la[e] > best) { best = la[e]; bi = e; }
      tv[k] = best; tix[k] = bi; used |= 1u << bi;
    }
    const float mx = tv[0];
    float s = 0.f, w4[4];
    for (int k = 0; k < 4; k++) { w4[k] = expf(tv[k] - mx); s += w4[k]; }
    float out12[12];
#pragma unroll
    for (int e = 0; e < 12; e++) out12[e] = 0.f;
    for (int k = 0; k < 4; k++) out12[tix[k]] = w4[k] / s;
#pragma unroll
    for (int e = 0; e < 12; e++) wA[b * 12 + e] = out12[e];
    float mg = lg[0];
    for (int e = 1; e < 6; e++) mg = fmaxf(mg, lg[e]);
    float sg = 0.f, wg6[6];
    for (int e = 0; e < 6; e++) { wg6[e] = expf(lg[e] - mg); sg += wg6[e]; }
    float H = 0.f;
    for (int e = 0; e < 6; e++) {
      const float w = wg6[e] / sg;
      wG[b * 6 + e] = w;
      H -= w * logf(w + 1e-8f);
    }
    ent[b] = H;
  }
}

// pt0[b] = sum((out_plus-out_minus)^2); tsum0 += pt0[b]
__global__ __launch_bounds__(256) void tension0_kernel(
    const float* __restrict__ op, const float* __restrict__ om,
    float* __restrict__ pt0, float* __restrict__ ts0) {
  const long b = blockIdx.x;
  const int t = threadIdx.x;
  const float4 a = *(const float4*)(op + b * 1024 + t * 4);
  const float4 c = *(const float4*)(om + b * 1024 + t * 4);
  const float dx = a.x - c.x, dy = a.y - c.y, dz = a.z - c.z, dw = a.w - c.w;
  float s = dx * dx + dy * dy + dz * dz + dw * dw;
#pragma unroll
  for (int m = 1; m < 64; m <<= 1) s += __shfl_xor(s, m);
  __shared__ float rw[4];
  if ((t & 63) == 0) rw[t >> 6] = s;
  __syncthreads();
  if (t == 0) {
    const float tot = rw[0] + rw[1] + rw[2] + rw[3];
    pt0[b] = tot;
    atomicAdd(ts0, tot);
  }
}

// h_sm[b][j] = tanh(t*w1[0][j] + delta*w1[1][j] + (step/3)*w1[2][j] + b1[j])
__global__ __launch_bounds__(256) void hsm_kernel(
    const float* __restrict__ pt, const float* __restrict__ tsum,
    const float* __restrict__ w1, const float* __restrict__ b1,
    f16* __restrict__ o, int step) {
  const long idx = (long)blockIdx.x * 256 + threadIdx.x;
  const int j = (int)(idx & 2047);
  const long b = idx >> 11;
  const float t = pt[b];
  const float delta = (step == 0) ? 0.f : (t - tsum[0] * (1.f / 2048.f));
  const float st = (float)step * (1.f / 3.f);
  const float v = tanhf(t * w1[j] + delta * w1[2048 + j] + st * w1[4096 + j] + b1[j]);
  o[idx] = (f16)v;
}

__global__ __launch_bounds__(256) void aux_kernel(const float* __restrict__ ent,
                                                  const float* __restrict__ tsum,
                                                  float* __restrict__ out) {
  const int t = threadIdx.x;
  float s = 0.f;
  for (int i = t; i < 2048; i += 256) s += ent[i];
#pragma unroll
  for (int m = 1; m < 64; m <<= 1) s += __shfl_xor(s, m);
  __shared__ float rw[4];
  if ((t & 63) == 0) rw[t >> 6] = s;
  __syncthreads();
  if (t == 0) {
    const float h = (rw[0] + rw[1] + rw[2] + rw[3]) * (1.f / 2048.f);
    const float d = h - 1.0114042647f;  // H({1/2,1/3,1/6}) nats
    const float el = d * d;
    const float t0 = tsum[0] * (1.f / 2048.f), t1 = tsum[1] * (1.f / 2048.f);
    const float t2 = tsum[2] * (1.f / 2048.f), t3 = tsum[3] * (1.f / 2048.f);
    const float conv = (fabsf(t1 - t0) + fabsf(t2 - t1) + fabsf(t3 - t2)) * (1.f / 3.f);
    out[0] = el + 0.001f * conv;
  }
}

// ---------------------------------------------------------------- GEMM

struct GA {
  const f16* A; long lda;
  const f16* B; long ldb; long zB;
  int K;
  float* Cf; f16* Ch; long ldc; long zC;
  const float* bias; long zbias;
  const float* w; int ws;
  const float* op; const float* om;
  const float* pt; const float* ts;
  float* pt_out; float* tsum_out;
};

// C = A (MxK, fp16) * B^T (Bt is [N][K] fp16). BN=128 fixed, BK=32, 4 waves.
// EPI: 0 = bias+relu+row-gate -> f16 (h_scaled, z=expert)
//      1 = + sum_e w[b,e]*ba2[e][n] -> fp32 (out_plus/out_minus)
//      2 = tanh(+bias) -> f16 (self_state)
//      3 = rep+acc+bias -> f16 modified + row sumsq atomics (tension)
//      4 = output epilogue -> fp32 d_out
template <int BM, int EPI>
__global__ __launch_bounds__(256) void gemm(GA a) {
  constexpr int TM = BM / 32;
  __shared__ f16 Al[BM * 32];
  __shared__ f16 Bl[128 * 32];
  const int tid = threadIdx.x;
  const int wave = tid >> 6, lane = tid & 63;
  const int wm = wave & 1, wn = wave >> 1;
  const int l16 = lane & 15, q = lane >> 4;
  const long m0 = (long)blockIdx.y * BM;
  const long n0 = (long)blockIdx.x * 128;
  const int z = blockIdx.z;
  const f16* Ap = a.A + m0 * a.lda;
  const f16* Bp = a.B + (long)z * a.zB + n0 * a.ldb;

  f32x4 acc[TM][4] = {};

  const int nk = a.K >> 5;
  for (int kk = 0; kk < nk; ++kk) {
    const long k0 = (long)kk * 32;
    __syncthreads();
#pragma unroll
    for (int r = 0; r < BM / 64; r++) {
      const int idx = r * 256 + tid;
      LOAD_LDS16(Ap + (long)(idx >> 2) * a.lda + k0 + (idx & 3) * 8, &Al[idx * 8]);
    }
#pragma unroll
    for (int r = 0; r < 2; r++) {
      const int idx = r * 256 + tid;
      LOAD_LDS16(Bp + (long)(idx >> 2) * a.ldb + k0 + (idx & 3) * 8, &Bl[idx * 8]);
    }
    __syncthreads();
    f16x8 av[TM], bv[4];
#pragma unroll
    for (int i = 0; i < TM; i++)
      av[i] = *(const f16x8*)&Al[(wm * (BM / 2) + i * 16 + l16) * 32 + q * 8];
#pragma unroll
    for (int j = 0; j < 4; j++)
      bv[j] = *(const f16x8*)&Bl[(wn * 64 + j * 16 + l16) * 32 + q * 8];
#pragma unroll
    for (int i = 0; i < TM; i++)
#pragma unroll
      for (int j = 0; j < 4; j++)
        acc[i][j] = __builtin_amdgcn_mfma_f32_16x16x32_f16(av[i], bv[j], acc[i][j], 0, 0, 0);
  }

  // epilogue. C/D layout: row = q*4+reg, col = lane&15 (m89/m91 verified)
  if constexpr (EPI == 0) {
    const float* bias = a.bias + (long)z * a.zbias;
    f16* C = a.Ch + (long)z * a.zC;
#pragma unroll
    for (int i = 0; i < TM; i++) {
#pragma unroll
      for (int r = 0; r < 4; r++) {
        const long gr = m0 + wm * (BM / 2) + i * 16 + q * 4 + r;
        const float wv = a.w[gr * a.ws + z];
#pragma unroll
        for (int j = 0; j < 4; j++) {
          const int gc = (int)n0 + wn * 64 + j * 16 + l16;
          float v = acc[i][j][r] + bias[gc];
          v = fmaxf(v, 0.f) * wv;
          C[gr * a.ldc + gc] = (f16)v;
        }
      }
    }
  } else if constexpr (EPI == 1) {
#pragma unroll
    for (int i = 0; i < TM; i++) {
#pragma unroll
      for (int r = 0; r < 4; r++) {
        const long gr = m0 + wm * (BM / 2) + i * 16 + q * 4 + r;
        float wrow[12];
        for (int e = 0; e < a.ws; e++) wrow[e] = a.w[gr * a.ws + e];
#pragma unroll
        for (int j = 0; j < 4; j++) {
          const int gc = (int)n0 + wn * 64 + j * 16 + l16;
          float bt = 0.f;
          for (int e = 0; e < a.ws; e++) bt += wrow[e] * a.bias[e * 1024 + gc];
          a.Cf[gr * 1024 + gc] = acc[i][j][r] + bt;
        }
      }
    }
  } else if constexpr (EPI == 2) {
#pragma unroll
    for (int i = 0; i < TM; i++) {
#pragma unroll
      for (int r = 0; r < 4; r++) {
        const long gr = m0 + wm * (BM / 2) + i * 16 + q * 4 + r;
#pragma unroll
        for (int j = 0; j < 4; j++) {
          const int gc = (int)n0 + wn * 64 + j * 16 + l16;
          a.Ch[gr * 1024 + gc] = (f16)tanhf(acc[i][j][r] + a.bias[gc]);
        }
      }
    }
  } else if constexpr (EPI == 3) {
#pragma unroll
    for (int i = 0; i < TM; i++) {
#pragma unroll
      for (int r = 0; r < 4; r++) {
        const long gr = m0 + wm * (BM / 2) + i * 16 + q * 4 + r;
        float ss = 0.f;
#pragma unroll
        for (int j = 0; j < 4; j++) {
          const int gc = (int)n0 + wn * 64 + j * 16 + l16;
          const long ix = gr * 1024 + gc;
          const float v = (a.op[ix] - a.om[ix]) + acc[i][j][r] + a.bias[gc];
          a.Ch[ix] = (f16)v;
          ss += v * v;
        }
        ss += __shfl_xor(ss, 1); ss += __shfl_xor(ss, 2);
        ss += __shfl_xor(ss, 4); ss += __shfl_xor(ss, 8);
        if (l16 == 0) {
          atomicAdd(a.pt_out + gr, ss);
          atomicAdd(a.tsum_out, ss);
        }
      }
    }
  } else {  // EPI == 4
    const float tsc = a.ts[0];
#pragma unroll
    for (int i = 0; i < TM; i++) {
#pragma unroll
      for (int r = 0; r < 4; r++) {
        const long gr = m0 + wm * (BM / 2) + i * 16 + q * 4 + r;
        const float sq = sqrtf(a.pt[gr] + 1e-8f) * tsc;
#pragma unroll
        for (int j = 0; j < 4; j++) {
          const int gc = (int)n0 + wn * 64 + j * 16 + l16;
          const long ix = gr * 1024 + gc;
          const float v = tanhf(acc[i][j][r] + a.bias[gc]);
          a.Cf[ix] = 0.5f * (a.op[ix] + a.om[ix]) + sq * v;
        }
      }
    }
  }
}

// ---------------------------------------------------------------- launcher

extern "C" void kernel_launch(void* const* d_in, const int* in_sizes, int n_in,
                              void* d_out, int out_size, void* d_ws, size_t ws_size,
                              hipStream_t stream) {
  (void)in_sizes; (void)n_in; (void)out_size; (void)ws_size;
  const float* x    = (const float*)d_in[0];
  const float* gaw  = (const float*)d_in[1];
  const float* gab  = (const float*)d_in[2];
  const float* wa1  = (const float*)d_in[3];
  const float* ba1  = (const float*)d_in[4];
  const float* wa2  = (const float*)d_in[5];
  const float* ba2  = (const float*)d_in[6];
  const float* ggw  = (const float*)d_in[7];
  const float* ggb  = (const float*)d_in[8];
  const float* wg1  = (const float*)d_in[9];
  const float* bg1  = (const float*)d_in[10];
  const float* wg2  = (const float*)d_in[11];
  const float* bg2  = (const float*)d_in[12];
  const float* smw1 = (const float*)d_in[13];
  const float* smb1 = (const float*)d_in[14];
  const float* smw2 = (const float*)d_in[15];
  const float* smb2 = (const float*)d_in[16];
  const float* siw  = (const float*)d_in[17];
  const float* sib  = (const float*)d_in[18];
  const float* ftw  = (const float*)d_in[19];
  const float* ftb  = (const float*)d_in[20];
  const float* tsc  = (const float*)d_in[21];
  // d_in[22] = n_steps (==3, hard-coded)

  char* p = (char*)d_ws;
  size_t off = 0;
  auto alloc = [&](size_t bytes) -> char* {
    char* r = p + off;
    off = (off + bytes + 255) & ~(size_t)255;
    return r;
  };
  f16* xb     = (f16*)alloc(2048UL * 1024 * 2);
  f16* w1t    = (f16*)alloc(18UL * 2048 * 1024 * 2);  // wa1t(12)+wg1t(6); later wa2t+wg2t
  f16* smw2t  = (f16*)alloc(1024UL * 2048 * 2);
  f16* sit    = (f16*)alloc(1024UL * 1024 * 2);
  f16* ftt    = (f16*)alloc(1024UL * 1024 * 2);
  f16* hA     = (f16*)alloc(2048UL * 24576 * 2);
  f16* hG     = (f16*)alloc(2048UL * 12288 * 2);
  float* outP = (float*)alloc(2048UL * 1024 * 4);
  float* outM = (float*)alloc(2048UL * 1024 * 4);
  f16* hsmb   = (f16*)alloc(2048UL * 2048 * 2);
  f16* sst    = (f16*)alloc(2048UL * 1024 * 2);
  f16* modb   = (f16*)alloc(2048UL * 1024 * 2);
  float* wAb  = (float*)alloc(2048 * 12 * 4);
  float* wGb  = (float*)alloc(2048 * 6 * 4);
  float* entb = (float*)alloc(2048 * 4);
  float* ptb  = (float*)alloc(4 * 2048 * 4);
  float* tsb  = (float*)alloc(4 * 4);

  f16* wa1t = w1t;
  f16* wg1t = w1t + 12UL * 2048 * 1024;
  f16* wa2t = w1t;                       // reused AFTER GEMM1 (exact size match)
  f16* wg2t = w1t + 1024UL * 24576;

  // zero tension accumulators (ptb..tsb contiguous)
  hipMemsetAsync(ptb, 0, 4 * 2048 * 4 + 16, stream);

  // weight conversion + transpose to [N][K] fp16
  transpose_cast<<<dim3(64, 32, 12), 256, 0, stream>>>(wa1, wa1t, 1024, 2048,
      1024L * 2048, 2048L * 1024, 1024);
  transpose_cast<<<dim3(64, 32, 6), 256, 0, stream>>>(wg1, wg1t, 1024, 2048,
      1024L * 2048, 2048L * 1024, 1024);
  transpose_cast<<<dim3(32, 64, 1), 256, 0, stream>>>(smw2, smw2t, 2048, 1024, 0, 0, 2048);
  transpose_cast<<<dim3(32, 32, 1), 256, 0, stream>>>(siw, sit, 1024, 1024, 0, 0, 1024);
  transpose_cast<<<dim3(32, 32, 1), 256, 0, stream>>>(ftw, ftt, 1024, 1024, 0, 0, 1024);
  castx_kernel<<<2048, 256, 0, stream>>>(x, xb);
  gating_kernel<<<2048, 256, 0, stream>>>(x, gaw, gab, ggw, ggb, wAb, wGb, entb);

  // GEMM1: h_scaled[e] = w[b,e] * relu(x @ w1[e] + b1[e])
  GA g{};
  g.A = xb; g.lda = 1024; g.B = wa1t; g.ldb = 1024; g.zB = 2048L * 1024; g.K = 1024;
  g.Ch = hA; g.ldc = 24576; g.zC = 2048; g.bias = ba1; g.zbias = 2048;
  g.w = wAb; g.ws = 12;
  gemm<128, 0><<<dim3(16, 16, 12), 256, 0, stream>>>(g);
  g.B = wg1t; g.Ch = hG; g.ldc = 12288; g.bias = bg1; g.w = wGb; g.ws = 6;
  gemm<128, 0><<<dim3(16, 16, 6), 256, 0, stream>>>(g);

  // now wa1t/wg1t are dead: convert second-layer weights into the same region
  transpose_cast<<<dim3(32, 64, 12), 256, 0, stream>>>(wa2, wa2t, 2048, 1024,
      2048L * 1024, 2048, 24576);
  transpose_cast<<<dim3(32, 64, 6), 256, 0, stream>>>(wg2, wg2t, 2048, 1024,
      2048L * 1024, 2048, 12288);

  // GEMM2: flat K over experts -> out_plus / out_minus (fp32)
  GA g2{};
  g2.A = hA; g2.lda = 24576; g2.B = wa2t; g2.ldb = 24576; g2.K = 24576;
  g2.Cf = outP; g2.ldc = 1024; g2.bias = ba2; g2.w = wAb; g2.ws = 12;
  gemm<64, 1><<<dim3(8, 32, 1), 256, 0, stream>>>(g2);
  g2.A = hG; g2.lda = 12288; g2.B = wg2t; g2.ldb = 12288; g2.K = 12288;
  g2.Cf = outM; g2.bias = bg2; g2.w = wGb; g2.ws = 6;
  gemm<64, 1><<<dim3(8, 32, 1), 256, 0, stream>>>(g2);

  tension0_kernel<<<2048, 256, 0, stream>>>(outP, outM, ptb, tsb);

  for (int s = 0; s < 3; s++) {
    hsm_kernel<<<16384, 256, 0, stream>>>(ptb + s * 2048, tsb + s, smw1, smb1, hsmb, s);
    GA g3{};
    g3.A = hsmb; g3.lda = 2048; g3.B = smw2t; g3.ldb = 2048; g3.K = 2048;
    g3.Ch = sst; g3.ldc = 1024; g3.bias = smb2;
    gemm<64, 2><<<dim3(8, 32, 1), 256, 0, stream>>>(g3);
    GA g4{};
    g4.A = sst; g4.lda = 1024; g4.B = sit; g4.ldb = 1024; g4.K = 1024;
    g4.Ch = modb; g4.ldc = 1024; g4.bias = sib; g4.op = outP; g4.om = outM;
    g4.pt_out = ptb + (s + 1) * 2048; g4.tsum_out = tsb + (s + 1);
    gemm<64, 3><<<dim3(8, 32, 1), 256, 0, stream>>>(g4);
  }

  GA g5{};
  g5.A = modb; g5.lda = 1024; g5.B = ftt; g5.ldb = 1024; g5.K = 1024;
  g5.Cf = (float*)d_out; g5.ldc = 1024; g5.bias = ftb; g5.op = outP; g5.om = outM;
  g5.pt = ptb + 3 * 2048; g5.ts = tsc;
  gemm<64, 4><<<dim3(8, 32, 1), 256, 0, stream>>>(g5);

  aux_kernel<<<1, 256, 0, stream>>>(entb, tsb, (float*)d_out + 2048UL * 1024);
}

// Round 2
// 1402.610 us; speedup vs baseline: 1.4142x; 1.4142x over previous
//
#include <hip/hip_runtime.h>

typedef _Float16 f16;
typedef f16  f16x8 __attribute__((ext_vector_type(8)));
typedef f16  f16x4 __attribute__((ext_vector_type(4)));
typedef float f32x4 __attribute__((ext_vector_type(4)));

#define LOAD_LDS16(gp, lp) __builtin_amdgcn_global_load_lds( \
    (const __attribute__((address_space(1))) void*)(gp),     \
    (__attribute__((address_space(3))) void*)(lp), 16, 0, 0)

// ---------------------------------------------------------------- helpers

__global__ __launch_bounds__(256) void castx_kernel(const float* __restrict__ x,
                                                    f16* __restrict__ o) {
  long i = ((long)blockIdx.x * 256 + threadIdx.x) * 4;
  const float4 v = *(const float4*)(x + i);
  f16x4 h; h.x = (f16)v.x; h.y = (f16)v.y; h.z = (f16)v.z; h.w = (f16)v.w;
  *(f16x4*)(o + i) = h;
}

// src [z][R][C] fp32  ->  dst (+z*dbatch) [c][r] fp16 with row stride dld
__global__ __launch_bounds__(256) void transpose_cast(const float* __restrict__ src,
                                                      f16* __restrict__ dst,
                                                      int R, int C, long sbatch,
                                                      long dbatch, int dld) {
  __shared__ float tile[32][33];
  const int zc = blockIdx.x * 32;   // src col tile
  const int zr = blockIdx.y * 32;   // src row tile
  const int z  = blockIdx.z;
  const float* s = src + (long)z * sbatch;
  f16* d = dst + (long)z * dbatch;
  const int tx = threadIdx.x & 31, ty = threadIdx.x >> 5;  // ty in [0,8)
#pragma unroll
  for (int rr = 0; rr < 32; rr += 8)
    tile[ty + rr][tx] = s[(long)(zr + ty + rr) * C + (zc + tx)];
  __syncthreads();
#pragma unroll
  for (int rr = 0; rr < 32; rr += 8)
    d[(long)(zc + ty + rr) * dld + (zr + tx)] = (f16)tile[tx][ty + rr];
}

// gating: logits, top-4-of-12 softmax, dense softmax(6) + entropy. fp32 exact.
__global__ __launch_bounds__(256) void gating_kernel(
    const float* __restrict__ x, const float* __restrict__ gaw,
    const float* __restrict__ gab, const float* __restrict__ ggw,
    const float* __restrict__ ggb, float* __restrict__ wA,
    float* __restrict__ wG, float* __restrict__ ent) {
  const int b = blockIdx.x, t = threadIdx.x;
  const float* xr = x + (long)b * 1024;
  float pa[12], pg[6];
#pragma unroll
  for (int e = 0; e < 12; e++) pa[e] = 0.f;
#pragma unroll
  for (int e = 0; e < 6; e++) pg[e] = 0.f;
  const int i0 = t * 4;
  const float4 xv = *(const float4*)(xr + i0);
  const float xs[4] = {xv.x, xv.y, xv.z, xv.w};
#pragma unroll
  for (int u = 0; u < 4; u++) {
    const float xi = xs[u];
    const float* ga = gaw + (long)(i0 + u) * 12;
    const float* gg = ggw + (long)(i0 + u) * 6;
#pragma unroll
    for (int e = 0; e < 12; e++) pa[e] += xi * ga[e];
#pragma unroll
    for (int e = 0; e < 6; e++) pg[e] += xi * gg[e];
  }
#pragma unroll
  for (int e = 0; e < 12; e++)
    for (int m = 1; m < 64; m <<= 1) pa[e] += __shfl_xor(pa[e], m);
#pragma unroll
  for (int e = 0; e < 6; e++)
    for (int m = 1; m < 64; m <<= 1) pg[e] += __shfl_xor(pg[e], m);
  __shared__ float rw[4][18];
  const int lane = t & 63, wv = t >> 6;
  if (lane == 0) {
#pragma unroll
    for (int e = 0; e < 12; e++) rw[wv][e] = pa[e];
#pragma unroll
    for (int e = 0; e < 6; e++) rw[wv][12 + e] = pg[e];
  }
  __syncthreads();
  if (t == 0) {
    float la[12], lg[6];
#pragma unroll
    for (int e = 0; e < 12; e++)
      la[e] = rw[0][e] + rw[1][e] + rw[2][e] + rw[3][e] + gab[e];
#pragma unroll
    for (int e = 0; e < 6; e++)
      lg[e] = rw[0][12 + e] + rw[1][12 + e] + rw[2][12 + e] + rw[3][12 + e] + ggb[e];
    // top-4 of 12 (first-max on ties, matches lax.top_k)
    unsigned used = 0; float tv[4]; int tix[4];
    for (int k = 0; k < 4; k++) {
      float best = -3.4e38f; int bi = 0;
      for (int e = 0; e < 12; e++)
        if (!((used >> e) & 1u) && la[e] > best) { best = la[e]; bi = e; }
      tv[k] = best; tix[k] = bi; used |= 1u << bi;
    }
    const float mx = tv[0];
    float s = 0.f, w4[4];
    for (int k = 0; k < 4; k++) { w4[k] = expf(tv[k] - mx); s += w4[k]; }
    float out12[12];
#pragma unroll
    for (int e = 0; e < 12; e++) out12[e] = 0.f;
    for (int k = 0; k < 4; k++) out12[tix[k]] = w4[k] / s;
#pragma unroll
    for (int e = 0; e < 12; e++) wA[b * 12 + e] = out12[e];
    float mg = lg[0];
    for (int e = 1; e < 6; e++) mg = fmaxf(mg, lg[e]);
    float sg = 0.f, wg6[6];
    for (int e = 0; e < 6; e++) { wg6[e] = expf(lg[e] - mg); sg += wg6[e]; }
    float H = 0.f;
    for (int e = 0; e < 6; e++) {
      const float w = wg6[e] / sg;
      wG[b * 6 + e] = w;
      H -= w * logf(w + 1e-8f);
    }
    ent[b] = H;
  }
}

// pt0[b] = sum((out_plus-out_minus)^2); tsum0 += pt0[b]
__global__ __launch_bounds__(256) void tension0_kernel(
    const float* __restrict__ op, const float* __restrict__ om,
    float* __restrict__ pt0, float* __restrict__ ts0) {
  const long b = blockIdx.x;
  const int t = threadIdx.x;
  const float4 a = *(const float4*)(op + b * 1024 + t * 4);
  const float4 c = *(const float4*)(om + b * 1024 + t * 4);
  const float dx = a.x - c.x, dy = a.y - c.y, dz = a.z - c.z, dw = a.w - c.w;
  float s = dx * dx + dy * dy + dz * dz + dw * dw;
#pragma unroll
  for (int m = 1; m < 64; m <<= 1) s += __shfl_xor(s, m);
  __shared__ float rw[4];
  if ((t & 63) == 0) rw[t >> 6] = s;
  __syncthreads();
  if (t == 0) {
    const float tot = rw[0] + rw[1] + rw[2] + rw[3];
    pt0[b] = tot;
    atomicAdd(ts0, tot);
  }
}

// h_sm[b][j] = tanh(t*w1[0][j] + delta*w1[1][j] + (step/3)*w1[2][j] + b1[j])
__global__ __launch_bounds__(256) void hsm_kernel(
    const float* __restrict__ pt, const float* __restrict__ tsum,
    const float* __restrict__ w1, const float* __restrict__ b1,
    f16* __restrict__ o, int step) {
  const long idx = (long)blockIdx.x * 256 + threadIdx.x;
  const int j = (int)(idx & 2047);
  const long b = idx >> 11;
  const float t = pt[b];
  const float delta = (step == 0) ? 0.f : (t - tsum[0] * (1.f / 2048.f));
  const float st = (float)step * (1.f / 3.f);
  const float v = tanhf(t * w1[j] + delta * w1[2048 + j] + st * w1[4096 + j] + b1[j]);
  o[idx] = (f16)v;
}

__global__ __launch_bounds__(256) void aux_kernel(const float* __restrict__ ent,
                                                  const float* __restrict__ tsum,
                                                  float* __restrict__ out) {
  const int t = threadIdx.x;
  float s = 0.f;
  for (int i = t; i < 2048; i += 256) s += ent[i];
#pragma unroll
  for (int m = 1; m < 64; m <<= 1) s += __shfl_xor(s, m);
  __shared__ float rw[4];
  if ((t & 63) == 0) rw[t >> 6] = s;
  __syncthreads();
  if (t == 0) {
    const float h = (rw[0] + rw[1] + rw[2] + rw[3]) * (1.f / 2048.f);
    const float d = h - 1.0114042647f;  // H({1/2,1/3,1/6}) nats
    const float el = d * d;
    const float t0 = tsum[0] * (1.f / 2048.f), t1 = tsum[1] * (1.f / 2048.f);
    const float t2 = tsum[2] * (1.f / 2048.f), t3 = tsum[3] * (1.f / 2048.f);
    const float conv = (fabsf(t1 - t0) + fabsf(t2 - t1) + fabsf(t3 - t2)) * (1.f / 3.f);
    out[0] = el + 0.001f * conv;
  }
}

// ---------------------------------------------------------------- GEMM

struct GA {
  const f16* A; long lda; long zA;     // zA: A element offset per blockIdx.z (split-K)
  const f16* B; long ldb; long zB;     // zB: B element offset per blockIdx.z (expert or split)
  int nk;                              // K iterations (BK=32) per block
  float* Cf; f16* Ch; long ldc; long zC;
  const float* bias; long zbias;
  const float* w; int ws;
  const float* op; const float* om;
  const float* pt; const float* ts;
  float* pt_out; float* tsum_out;
};

// C = A (MxK, fp16) * B^T (Bt is [N][K] fp16). BK=32, 4 waves in 2x2 grid.
// EPI: 0 = bias+relu+row-gate -> f16 (h_scaled, z=expert)
//      1 = split-K partial: atomicAdd fp32 (+ sum_e w*ba2 bias on z==0)
//      2 = tanh(+bias) -> f16 (self_state)
//      3 = rep+acc+bias -> f16 modified + row sumsq atomics (tension)
//      4 = output epilogue -> fp32 d_out
template <int BM, int BN, int EPI>
__global__ __launch_bounds__(256) void gemm(GA a) {
  constexpr int TM = BM / 32;
  constexpr int TN = BN / 32;
  __shared__ f16 Al[BM * 32];
  __shared__ f16 Bl[BN * 32];
  const int tid = threadIdx.x;
  const int wave = tid >> 6, lane = tid & 63;
  const int wm = wave & 1, wn = wave >> 1;
  const int l16 = lane & 15, q = lane >> 4;
  const long m0 = (long)blockIdx.y * BM;
  const long n0 = (long)blockIdx.x * BN;
  const int z = blockIdx.z;
  const f16* Ap = a.A + m0 * a.lda + (long)z * a.zA;
  const f16* Bp = a.B + n0 * a.ldb + (long)z * a.zB;

  f32x4 acc[TM][TN] = {};

  for (int kk = 0; kk < a.nk; ++kk) {
    const long k0 = (long)kk * 32;
    __syncthreads();
#pragma unroll
    for (int r = 0; r < BM / 64; r++) {
      const int idx = r * 256 + tid;
      LOAD_LDS16(Ap + (long)(idx >> 2) * a.lda + k0 + (idx & 3) * 8, &Al[idx * 8]);
    }
#pragma unroll
    for (int r = 0; r < BN / 64; r++) {
      const int idx = r * 256 + tid;
      LOAD_LDS16(Bp + (long)(idx >> 2) * a.ldb + k0 + (idx & 3) * 8, &Bl[idx * 8]);
    }
    __syncthreads();
    f16x8 av[TM], bv[TN];
#pragma unroll
    for (int i = 0; i < TM; i++)
      av[i] = *(const f16x8*)&Al[(wm * (BM / 2) + i * 16 + l16) * 32 + q * 8];
#pragma unroll
    for (int j = 0; j < TN; j++)
      bv[j] = *(const f16x8*)&Bl[(wn * (BN / 2) + j * 16 + l16) * 32 + q * 8];
#pragma unroll
    for (int i = 0; i < TM; i++)
#pragma unroll
      for (int j = 0; j < TN; j++)
        acc[i][j] = __builtin_amdgcn_mfma_f32_16x16x32_f16(av[i], bv[j], acc[i][j], 0, 0, 0);
  }

  // epilogue. C/D layout: row = q*4+reg, col = lane&15 (m89/m91 verified)
  if constexpr (EPI == 0) {
    const float* bias = a.bias + (long)z * a.zbias;
    f16* C = a.Ch + (long)z * a.zC;
#pragma unroll
    for (int i = 0; i < TM; i++) {
#pragma unroll
      for (int r = 0; r < 4; r++) {
        const long gr = m0 + wm * (BM / 2) + i * 16 + q * 4 + r;
        const float wv = a.w[gr * a.ws + z];
#pragma unroll
        for (int j = 0; j < TN; j++) {
          const int gc = (int)n0 + wn * (BN / 2) + j * 16 + l16;
          float v = acc[i][j][r] + bias[gc];
          v = fmaxf(v, 0.f) * wv;
          C[gr * a.ldc + gc] = (f16)v;
        }
      }
    }
  } else if constexpr (EPI == 1) {
    const bool first = (z == 0);
#pragma unroll
    for (int i = 0; i < TM; i++) {
#pragma unroll
      for (int r = 0; r < 4; r++) {
        const long gr = m0 + wm * (BM / 2) + i * 16 + q * 4 + r;
        float wrow[12];
        if (first)
          for (int e = 0; e < a.ws; e++) wrow[e] = a.w[gr * a.ws + e];
#pragma unroll
        for (int j = 0; j < TN; j++) {
          const int gc = (int)n0 + wn * (BN / 2) + j * 16 + l16;
          float v = acc[i][j][r];
          if (first) {
            float bt = 0.f;
            for (int e = 0; e < a.ws; e++) bt += wrow[e] * a.bias[e * 1024 + gc];
            v += bt;
          }
          atomicAdd(&a.Cf[gr * 1024 + gc], v);
        }
      }
    }
  } else if constexpr (EPI == 2) {
#pragma unroll
    for (int i = 0; i < TM; i++) {
#pragma unroll
      for (int r = 0; r < 4; r++) {
        const long gr = m0 + wm * (BM / 2) + i * 16 + q * 4 + r;
#pragma unroll
        for (int j = 0; j < TN; j++) {
          const int gc = (int)n0 + wn * (BN / 2) + j * 16 + l16;
          a.Ch[gr * 1024 + gc] = (f16)tanhf(acc[i][j][r] + a.bias[gc]);
        }
      }
    }
  } else if constexpr (EPI == 3) {
    float wave_ss = 0.f;
#pragma unroll
    for (int i = 0; i < TM; i++) {
#pragma unroll
      for (int r = 0; r < 4; r++) {
        const long gr = m0 + wm * (BM / 2) + i * 16 + q * 4 + r;
        float ss = 0.f;
#pragma unroll
        for (int j = 0; j < TN; j++) {
          const int gc = (int)n0 + wn * (BN / 2) + j * 16 + l16;
          const long ix = gr * 1024 + gc;
          const float v = (a.op[ix] - a.om[ix]) + acc[i][j][r] + a.bias[gc];
          a.Ch[ix] = (f16)v;
          ss += v * v;
        }
        ss += __shfl_xor(ss, 1); ss += __shfl_xor(ss, 2);
        ss += __shfl_xor(ss, 4); ss += __shfl_xor(ss, 8);
        if (l16 == 0) {
          atomicAdd(a.pt_out + gr, ss);
          wave_ss += ss;
        }
      }
    }
    // one contended atomic per wave, not per row-tile
    wave_ss += __shfl_xor(wave_ss, 16);
    wave_ss += __shfl_xor(wave_ss, 32);
    if (lane == 0) atomicAdd(a.tsum_out, wave_ss);
  } else {  // EPI == 4
    const float tsc = a.ts[0];
#pragma unroll
    for (int i = 0; i < TM; i++) {
#pragma unroll
      for (int r = 0; r < 4; r++) {
        const long gr = m0 + wm * (BM / 2) + i * 16 + q * 4 + r;
        const float sq = sqrtf(a.pt[gr] + 1e-8f) * tsc;
#pragma unroll
        for (int j = 0; j < TN; j++) {
          const int gc = (int)n0 + wn * (BN / 2) + j * 16 + l16;
          const long ix = gr * 1024 + gc;
          const float v = tanhf(acc[i][j][r] + a.bias[gc]);
          a.Cf[ix] = 0.5f * (a.op[ix] + a.om[ix]) + sq * v;
        }
      }
    }
  }
}

// ---------------------------------------------------------------- launcher

extern "C" void kernel_launch(void* const* d_in, const int* in_sizes, int n_in,
                              void* d_out, int out_size, void* d_ws, size_t ws_size,
                              hipStream_t stream) {
  (void)in_sizes; (void)n_in; (void)out_size; (void)ws_size;
  const float* x    = (const float*)d_in[0];
  const float* gaw  = (const float*)d_in[1];
  const float* gab  = (const float*)d_in[2];
  const float* wa1  = (const float*)d_in[3];
  const float* ba1  = (const float*)d_in[4];
  const float* wa2  = (const float*)d_in[5];
  const float* ba2  = (const float*)d_in[6];
  const float* ggw  = (const float*)d_in[7];
  const float* ggb  = (const float*)d_in[8];
  const float* wg1  = (const float*)d_in[9];
  const float* bg1  = (const float*)d_in[10];
  const float* wg2  = (const float*)d_in[11];
  const float* bg2  = (const float*)d_in[12];
  const float* smw1 = (const float*)d_in[13];
  const float* smb1 = (const float*)d_in[14];
  const float* smw2 = (const float*)d_in[15];
  const float* smb2 = (const float*)d_in[16];
  const float* siw  = (const float*)d_in[17];
  const float* sib  = (const float*)d_in[18];
  const float* ftw  = (const float*)d_in[19];
  const float* ftb  = (const float*)d_in[20];
  const float* tsc  = (const float*)d_in[21];
  // d_in[22] = n_steps (==3, hard-coded)

  char* p = (char*)d_ws;
  size_t off = 0;
  auto alloc = [&](size_t bytes) -> char* {
    char* r = p + off;
    off = (off + bytes + 255) & ~(size_t)255;
    return r;
  };
  f16* xb     = (f16*)alloc(2048UL * 1024 * 2);
  f16* w1t    = (f16*)alloc(18UL * 2048 * 1024 * 2);  // wa1t(12)+wg1t(6); later wa2t+wg2t
  f16* smw2t  = (f16*)alloc(1024UL * 2048 * 2);
  f16* sit    = (f16*)alloc(1024UL * 1024 * 2);
  f16* ftt    = (f16*)alloc(1024UL * 1024 * 2);
  f16* hA     = (f16*)alloc(2048UL * 24576 * 2);
  f16* hG     = (f16*)alloc(2048UL * 12288 * 2);
  float* outP = (float*)alloc(2048UL * 1024 * 4);
  float* outM = (float*)alloc(2048UL * 1024 * 4);
  f16* hsmb   = (f16*)alloc(2048UL * 2048 * 2);
  f16* sst    = (f16*)alloc(2048UL * 1024 * 2);
  f16* modb   = (f16*)alloc(2048UL * 1024 * 2);
  float* wAb  = (float*)alloc(2048 * 12 * 4);
  float* wGb  = (float*)alloc(2048 * 6 * 4);
  float* entb = (float*)alloc(2048 * 4);
  float* ptb  = (float*)alloc(4 * 2048 * 4);
  float* tsb  = (float*)alloc(4 * 4);

  f16* wa1t = w1t;
  f16* wg1t = w1t + 12UL * 2048 * 1024;
  f16* wa2t = w1t;                       // reused AFTER GEMM1 (exact size match)
  f16* wg2t = w1t + 1024UL * 24576;

  // zero tension accumulators + split-K output accumulators
  hipMemsetAsync(ptb, 0, 4 * 2048 * 4 + 16, stream);
  hipMemsetAsync(outP, 0, 2 * 2048UL * 1024 * 4, stream);  // outP+outM contiguous

  // weight conversion + transpose to [N][K] fp16
  transpose_cast<<<dim3(64, 32, 12), 256, 0, stream>>>(wa1, wa1t, 1024, 2048,
      1024L * 2048, 2048L * 1024, 1024);
  transpose_cast<<<dim3(64, 32, 6), 256, 0, stream>>>(wg1, wg1t, 1024, 2048,
      1024L * 2048, 2048L * 1024, 1024);
  transpose_cast<<<dim3(32, 64, 1), 256, 0, stream>>>(smw2, smw2t, 2048, 1024, 0, 0, 2048);
  transpose_cast<<<dim3(32, 32, 1), 256, 0, stream>>>(siw, sit, 1024, 1024, 0, 0, 1024);
  transpose_cast<<<dim3(32, 32, 1), 256, 0, stream>>>(ftw, ftt, 1024, 1024, 0, 0, 1024);
  castx_kernel<<<2048, 256, 0, stream>>>(x, xb);
  gating_kernel<<<2048, 256, 0, stream>>>(x, gaw, gab, ggw, ggb, wAb, wGb, entb);

  // GEMM1: h_scaled[e] = w[b,e] * relu(x @ w1[e] + b1[e])
  GA g{};
  g.A = xb; g.lda = 1024; g.zA = 0;
  g.B = wa1t; g.ldb = 1024; g.zB = 2048L * 1024; g.nk = 32;
  g.Ch = hA; g.ldc = 24576; g.zC = 2048; g.bias = ba1; g.zbias = 2048;
  g.w = wAb; g.ws = 12;
  gemm<128, 128, 0><<<dim3(16, 16, 12), 256, 0, stream>>>(g);
  g.B = wg1t; g.Ch = hG; g.ldc = 12288; g.bias = bg1; g.w = wGb; g.ws = 6;
  gemm<128, 128, 0><<<dim3(16, 16, 6), 256, 0, stream>>>(g);

  // now wa1t/wg1t are dead: convert second-layer weights into the same region
  transpose_cast<<<dim3(32, 64, 12), 256, 0, stream>>>(wa2, wa2t, 2048, 1024,
      2048L * 1024, 2048, 24576);
  transpose_cast<<<dim3(32, 64, 6), 256, 0, stream>>>(wg2, wg2t, 2048, 1024,
      2048L * 1024, 2048, 12288);

  // GEMM2: flat K over experts, split-K=8, fp32 atomic accumulate
  GA g2{};
  g2.A = hA; g2.lda = 24576; g2.zA = 3072;
  g2.B = wa2t; g2.ldb = 24576; g2.zB = 3072; g2.nk = 96;   // 8 * 3072 = 24576
  g2.Cf = outP; g2.ldc = 1024; g2.bias = ba2; g2.w = wAb; g2.ws = 12;
  gemm<128, 128, 1><<<dim3(8, 16, 8), 256, 0, stream>>>(g2);
  g2.A = hG; g2.lda = 12288; g2.zA = 1536;
  g2.B = wg2t; g2.ldb = 12288; g2.zB = 1536; g2.nk = 48;   // 8 * 1536 = 12288
  g2.Cf = outM; g2.bias = bg2; g2.w = wGb; g2.ws = 6;
  gemm<128, 128, 1><<<dim3(8, 16, 8), 256, 0, stream>>>(g2);

  tension0_kernel<<<2048, 256, 0, stream>>>(outP, outM, ptb, tsb);

  for (int s = 0; s < 3; s++) {
    hsm_kernel<<<16384, 256, 0, stream>>>(ptb + s * 2048, tsb + s, smw1, smb1, hsmb, s);
    GA g3{};
    g3.A = hsmb; g3.lda = 2048; g3.zA = 0;
    g3.B = smw2t; g3.ldb = 2048; g3.zB = 0; g3.nk = 64;
    g3.Ch = sst; g3.ldc = 1024; g3.bias = smb2;
    gemm<64, 64, 2><<<dim3(16, 32, 1), 256, 0, stream>>>(g3);
    GA g4{};
    g4.A = sst; g4.lda = 1024; g4.zA = 0;
    g4.B = sit; g4.ldb = 1024; g4.zB = 0; g4.nk = 32;
    g4.Ch = modb; g4.ldc = 1024; g4.bias = sib; g4.op = outP; g4.om = outM;
    g4.pt_out = ptb + (s + 1) * 2048; g4.tsum_out = tsb + (s + 1);
    gemm<64, 64, 3><<<dim3(16, 32, 1), 256, 0, stream>>>(g4);
  }

  GA g5{};
  g5.A = modb; g5.lda = 1024; g5.zA = 0;
  g5.B = ftt; g5.ldb = 1024; g5.zB = 0; g5.nk = 32;
  g5.Cf = (float*)d_out; g5.ldc = 1024; g5.bias = ftb; g5.op = outP; g5.om = outM;
  g5.pt = ptb + 3 * 2048; g5.ts = tsc;
  gemm<64, 64, 4><<<dim3(16, 32, 1), 256, 0, stream>>>(g5);

  aux_kernel<<<1, 256, 0, stream>>>(entb, tsb, (float*)d_out + 2048UL * 1024);
}

// Round 3
// 1216.684 us; speedup vs baseline: 1.6303x; 1.1528x over previous
//
#include <hip/hip_runtime.h>

typedef _Float16 f16;
typedef f16  f16x8 __attribute__((ext_vector_type(8)));
typedef f16  f16x4 __attribute__((ext_vector_type(4)));
typedef float f32x4 __attribute__((ext_vector_type(4)));

#define LOAD_LDS16(gp, lp) __builtin_amdgcn_global_load_lds( \
    (const __attribute__((address_space(1))) void*)(gp),     \
    (__attribute__((address_space(3))) void*)(lp), 16, 0, 0)

// ---------------------------------------------------------------- helpers

__global__ __launch_bounds__(256) void castx_kernel(const float* __restrict__ x,
                                                    f16* __restrict__ o) {
  long i = ((long)blockIdx.x * 256 + threadIdx.x) * 4;
  const float4 v = *(const float4*)(x + i);
  f16x4 h; h.x = (f16)v.x; h.y = (f16)v.y; h.z = (f16)v.z; h.w = (f16)v.w;
  *(f16x4*)(o + i) = h;
}

// src [z][R][C] fp32  ->  dst (+z*dbatch) [c][r] fp16 with row stride dld
__global__ __launch_bounds__(256) void transpose_cast(const float* __restrict__ src,
                                                      f16* __restrict__ dst,
                                                      int R, int C, long sbatch,
                                                      long dbatch, int dld) {
  __shared__ float tile[32][33];
  const int zc = blockIdx.x * 32;   // src col tile
  const int zr = blockIdx.y * 32;   // src row tile
  const int z  = blockIdx.z;
  const float* s = src + (long)z * sbatch;
  f16* d = dst + (long)z * dbatch;
  const int tx = threadIdx.x & 31, ty = threadIdx.x >> 5;  // ty in [0,8)
#pragma unroll
  for (int rr = 0; rr < 32; rr += 8)
    tile[ty + rr][tx] = s[(long)(zr + ty + rr) * C + (zc + tx)];
  __syncthreads();
#pragma unroll
  for (int rr = 0; rr < 32; rr += 8)
    d[(long)(zc + ty + rr) * dld + (zr + tx)] = (f16)tile[tx][ty + rr];
}

// gating: logits, top-4-of-12 softmax (dense + routed lists), softmax(6)+entropy.
__global__ __launch_bounds__(256) void gating_kernel(
    const float* __restrict__ x, const float* __restrict__ gaw,
    const float* __restrict__ gab, const float* __restrict__ ggw,
    const float* __restrict__ ggb, float* __restrict__ wA,
    float* __restrict__ wG, float* __restrict__ ent,
    int* __restrict__ rows, float* __restrict__ gval, int* __restrict__ cnt) {
  const int b = blockIdx.x, t = threadIdx.x;
  const float* xr = x + (long)b * 1024;
  float pa[12], pg[6];
#pragma unroll
  for (int e = 0; e < 12; e++) pa[e] = 0.f;
#pragma unroll
  for (int e = 0; e < 6; e++) pg[e] = 0.f;
  const int i0 = t * 4;
  const float4 xv = *(const float4*)(xr + i0);
  const float xs[4] = {xv.x, xv.y, xv.z, xv.w};
#pragma unroll
  for (int u = 0; u < 4; u++) {
    const float xi = xs[u];
    const float* ga = gaw + (long)(i0 + u) * 12;
    const float* gg = ggw + (long)(i0 + u) * 6;
#pragma unroll
    for (int e = 0; e < 12; e++) pa[e] += xi * ga[e];
#pragma unroll
    for (int e = 0; e < 6; e++) pg[e] += xi * gg[e];
  }
#pragma unroll
  for (int e = 0; e < 12; e++)
    for (int m = 1; m < 64; m <<= 1) pa[e] += __shfl_xor(pa[e], m);
#pragma unroll
  for (int e = 0; e < 6; e++)
    for (int m = 1; m < 64; m <<= 1) pg[e] += __shfl_xor(pg[e], m);
  __shared__ float rw[4][18];
  const int lane = t & 63, wv = t >> 6;
  if (lane == 0) {
#pragma unroll
    for (int e = 0; e < 12; e++) rw[wv][e] = pa[e];
#pragma unroll
    for (int e = 0; e < 6; e++) rw[wv][12 + e] = pg[e];
  }
  __syncthreads();
  if (t == 0) {
    float la[12], lg[6];
#pragma unroll
    for (int e = 0; e < 12; e++)
      la[e] = rw[0][e] + rw[1][e] + rw[2][e] + rw[3][e] + gab[e];
#pragma unroll
    for (int e = 0; e < 6; e++)
      lg[e] = rw[0][12 + e] + rw[1][12 + e] + rw[2][12 + e] + rw[3][12 + e] + ggb[e];
    // top-4 of 12 (first-max on ties, matches lax.top_k)
    unsigned used = 0; float tv[4]; int tix[4];
    for (int k = 0; k < 4; k++) {
      float best = -3.4e38f; int bi = 0;
      for (int e = 0; e < 12; e++)
        if (!((used >> e) & 1u) && la[e] > best) { best = la[e]; bi = e; }
      tv[k] = best; tix[k] = bi; used |= 1u << bi;
    }
    const float mx = tv[0];
    float s = 0.f, w4[4];
    for (int k = 0; k < 4; k++) { w4[k] = expf(tv[k] - mx); s += w4[k]; }
    float out12[12];
#pragma unroll
    for (int e = 0; e < 12; e++) out12[e] = 0.f;
    for (int k = 0; k < 4; k++) {
      const float w = w4[k] / s;
      out12[tix[k]] = w;
      const int pos = atomicAdd(&cnt[tix[k]], 1);
      rows[tix[k] * 2048 + pos] = b;
      gval[tix[k] * 2048 + pos] = w;
    }
#pragma unroll
    for (int e = 0; e < 12; e++) wA[b * 12 + e] = out12[e];
    float mg = lg[0];
    for (int e = 1; e < 6; e++) mg = fmaxf(mg, lg[e]);
    float sg = 0.f, wg6[6];
    for (int e = 0; e < 6; e++) { wg6[e] = expf(lg[e] - mg); sg += wg6[e]; }
    float H = 0.f;
    for (int e = 0; e < 6; e++) {
      const float w = wg6[e] / sg;
      wG[b * 6 + e] = w;
      H -= w * logf(w + 1e-8f);
    }
    ent[b] = H;
  }
}

// finalize out_plus/out_minus with gate-weighted layer-2 biases, then
// pt0[b] = sum((op-om)^2); tsum0 += pt0[b]
__global__ __launch_bounds__(256) void tension0_kernel(
    float* __restrict__ op, float* __restrict__ om,
    const float* __restrict__ wA, const float* __restrict__ wG,
    const float* __restrict__ ba2, const float* __restrict__ bg2,
    float* __restrict__ pt0, float* __restrict__ ts0) {
  const long b = blockIdx.x;
  const int t = threadIdx.x;
  const int c = t * 4;
  float4 a = *(const float4*)(op + b * 1024 + c);
  float4 g = *(const float4*)(om + b * 1024 + c);
#pragma unroll
  for (int e = 0; e < 12; e++) {
    const float w = wA[b * 12 + e];
    const float4 bb = *(const float4*)(ba2 + e * 1024 + c);
    a.x += w * bb.x; a.y += w * bb.y; a.z += w * bb.z; a.w += w * bb.w;
  }
#pragma unroll
  for (int e = 0; e < 6; e++) {
    const float w = wG[b * 6 + e];
    const float4 bb = *(const float4*)(bg2 + e * 1024 + c);
    g.x += w * bb.x; g.y += w * bb.y; g.z += w * bb.z; g.w += w * bb.w;
  }
  *(float4*)(op + b * 1024 + c) = a;
  *(float4*)(om + b * 1024 + c) = g;
  const float dx = a.x - g.x, dy = a.y - g.y, dz = a.z - g.z, dw = a.w - g.w;
  float s = dx * dx + dy * dy + dz * dz + dw * dw;
#pragma unroll
  for (int m = 1; m < 64; m <<= 1) s += __shfl_xor(s, m);
  __shared__ float rw[4];
  if ((t & 63) == 0) rw[t >> 6] = s;
  __syncthreads();
  if (t == 0) {
    const float tot = rw[0] + rw[1] + rw[2] + rw[3];
    pt0[b] = tot;
    atomicAdd(ts0, tot);
  }
}

// h_sm: thread owns column j, iterates 64 rows, reuses w1 in registers
__global__ __launch_bounds__(256) void hsm_kernel(
    const float* __restrict__ pt, const float* __restrict__ tsum,
    const float* __restrict__ w1, const float* __restrict__ b1,
    f16* __restrict__ o, int step) {
  const int j = blockIdx.x * 256 + threadIdx.x;
  const int b0 = blockIdx.y * 64;
  const float u0 = w1[j], u1 = w1[2048 + j], u2 = w1[4096 + j], bb = b1[j];
  const float tm = tsum[0] * (1.f / 2048.f);
  const float st = (float)step * (1.f / 3.f);
#pragma unroll 4
  for (int r = 0; r < 64; r++) {
    const int b = b0 + r;
    const float t = pt[b];
    const float delta = (step == 0) ? 0.f : (t - tm);
    o[(long)b * 2048 + j] = (f16)tanhf(t * u0 + delta * u1 + st * u2 + bb);
  }
}

__global__ __launch_bounds__(256) void aux_kernel(const float* __restrict__ ent,
                                                  const float* __restrict__ tsum,
                                                  float* __restrict__ out) {
  const int t = threadIdx.x;
  float s = 0.f;
  for (int i = t; i < 2048; i += 256) s += ent[i];
#pragma unroll
  for (int m = 1; m < 64; m <<= 1) s += __shfl_xor(s, m);
  __shared__ float rw[4];
  if ((t & 63) == 0) rw[t >> 6] = s;
  __syncthreads();
  if (t == 0) {
    const float h = (rw[0] + rw[1] + rw[2] + rw[3]) * (1.f / 2048.f);
    const float d = h - 1.0114042647f;  // H({1/2,1/3,1/6}) nats
    const float el = d * d;
    const float t0 = tsum[0] * (1.f / 2048.f), t1 = tsum[1] * (1.f / 2048.f);
    const float t2 = tsum[2] * (1.f / 2048.f), t3 = tsum[3] * (1.f / 2048.f);
    const float conv = (fabsf(t1 - t0) + fabsf(t2 - t1) + fabsf(t3 - t2)) * (1.f / 3.f);
    out[0] = el + 0.001f * conv;
  }
}

// ---------------------------------------------------------------- GEMM

struct GA {
  const f16* A; long lda; long zA;
  const f16* B; long ldb; long zB;
  int nk;                              // K iterations (BK=32)
  float* Cf; f16* Ch; long ldc; long zC;
  const float* bias; long zbias;
  const float* w; int ws;
  const float* op; const float* om;
  const float* pt; const float* ts;
  float* pt_out; float* tsum_out;
  const int* rows; const float* gval; const int* cnt;   // MoE routing
};

// C = A (MxK, fp16) * B^T ([N][K] fp16). BK=32, 4 waves in 2x2 grid.
// EPI: 0 = bias+relu+row-gate (dense w) -> f16     (GEMM1-G)
//      1 = split-K partial: atomicAdd fp32         (GEMM2-G)
//      2 = tanh(+bias) -> f16                      (self_state)
//      3 = rep+acc+bias -> f16 + tension atomics
//      4 = output epilogue -> fp32 d_out
//      5 = routed GEMM1-A: gather rows, relu+gate, compact store
//      6 = routed GEMM2-A: scatter atomicAdd by row list
// SWZ: 0 = blockIdx 3-D as-is
//      1 = GEMM1-G  (1536): XCD owns (e,n) pairs, m fastest on-XCD
//      2 = GEMM2-G  (1024): XCD owns m-tiles {2k,2k+1}, n fastest
//      3 = GEMM1-A  (3072): XCD owns (e,n) pairs, m fastest
//      4 = GEMM2-A  (1536): XCD owns m-tiles {2k,2k+1}, n fastest
template <int BM, int BN, int EPI, int SWZ>
__global__ __launch_bounds__(256) void gemm(GA a) {
  constexpr int TM = BM / 32;
  constexpr int TN = BN / 32;
  __shared__ f16 Al[BM * 32];
  __shared__ f16 Bl[BN * 32];
  __shared__ int   Lrow[128];
  __shared__ float Lg[128];
  int bx, by, bz;
  if constexpr (SWZ == 0) {
    bx = blockIdx.x; by = blockIdx.y; bz = blockIdx.z;
  } else if constexpr (SWZ == 1) {
    const int id = blockIdx.x, k = id & 7, t = id >> 3;
    by = t & 15; const int pid = k * 12 + (t >> 4);
    bz = pid >> 4; bx = pid & 15;
  } else if constexpr (SWZ == 2) {
    const int id = blockIdx.x, k = id & 7, t = id >> 3;
    bx = t & 7; bz = (t >> 3) & 7; by = 2 * k + (t >> 6);
  } else if constexpr (SWZ == 3) {
    const int id = blockIdx.x, k = id & 7, t = id >> 3;
    by = t & 15; const int pid = k * 24 + (t >> 4);
    bz = pid >> 4; bx = pid & 15;
  } else {  // SWZ == 4
    const int id = blockIdx.x, k = id & 7, t = id >> 3;
    bx = t & 7; const int v = t >> 3;
    bz = v >> 1; by = 2 * k + (v & 1);
  }
  const int tid = threadIdx.x;
  const int wave = tid >> 6, lane = tid & 63;
  const int wm = wave & 1, wn = wave >> 1;
  const int l16 = lane & 15, q = lane >> 4;
  const long m0 = (long)by * BM;
  const long n0 = (long)bx * BN;
  const int z = bz;

  int cn = 0;
  if constexpr (EPI == 5 || EPI == 6) {
    cn = a.cnt[z];
    if ((int)m0 >= cn) return;           // block-uniform exit, before any barrier
  }
  if constexpr (EPI == 5) {
    if (tid < 128) {
      const int gi = (int)m0 + tid;
      Lrow[tid] = (gi < cn) ? a.rows[z * 2048 + gi] : 0;
      Lg[tid]   = (gi < cn) ? a.gval[z * 2048 + gi] : 0.f;
    }
  }

  const f16* Ap = a.A + m0 * a.lda + (long)z * a.zA;
  const f16* Bp = a.B + n0 * a.ldb + (long)z * a.zB;

  f32x4 acc[TM][TN] = {};

  for (int kk = 0; kk < a.nk; ++kk) {
    const long k0 = (long)kk * 32;
    __syncthreads();
#pragma unroll
    for (int r = 0; r < BM / 64; r++) {
      const int idx = r * 256 + tid;
      if constexpr (EPI == 5) {
        const int ridx = Lrow[idx >> 2];
        LOAD_LDS16(a.A + (long)ridx * a.lda + k0 + (idx & 3) * 8, &Al[idx * 8]);
      } else {
        LOAD_LDS16(Ap + (long)(idx >> 2) * a.lda + k0 + (idx & 3) * 8, &Al[idx * 8]);
      }
    }
#pragma unroll
    for (int r = 0; r < BN / 64; r++) {
      const int idx = r * 256 + tid;
      LOAD_LDS16(Bp + (long)(idx >> 2) * a.ldb + k0 + (idx & 3) * 8, &Bl[idx * 8]);
    }
    __syncthreads();
    f16x8 av[TM], bv[TN];
#pragma unroll
    for (int i = 0; i < TM; i++)
      av[i] = *(const f16x8*)&Al[(wm * (BM / 2) + i * 16 + l16) * 32 + q * 8];
#pragma unroll
    for (int j = 0; j < TN; j++)
      bv[j] = *(const f16x8*)&Bl[(wn * (BN / 2) + j * 16 + l16) * 32 + q * 8];
#pragma unroll
    for (int i = 0; i < TM; i++)
#pragma unroll
      for (int j = 0; j < TN; j++)
        acc[i][j] = __builtin_amdgcn_mfma_f32_16x16x32_f16(av[i], bv[j], acc[i][j], 0, 0, 0);
  }

  // epilogue. C/D layout: row = q*4+reg, col = lane&15 (m89/m91 verified)
  if constexpr (EPI == 0) {
    const float* bias = a.bias + (long)z * a.zbias;
    f16* C = a.Ch + (long)z * a.zC;
#pragma unroll
    for (int i = 0; i < TM; i++) {
#pragma unroll
      for (int r = 0; r < 4; r++) {
        const long gr = m0 + wm * (BM / 2) + i * 16 + q * 4 + r;
        const float wv = a.w[gr * a.ws + z];
#pragma unroll
        for (int j = 0; j < TN; j++) {
          const int gc = (int)n0 + wn * (BN / 2) + j * 16 + l16;
          float v = acc[i][j][r] + bias[gc];
          v = fmaxf(v, 0.f) * wv;
          C[gr * a.ldc + gc] = (f16)v;
        }
      }
    }
  } else if constexpr (EPI == 1) {
#pragma unroll
    for (int i = 0; i < TM; i++) {
#pragma unroll
      for (int r = 0; r < 4; r++) {
        const long gr = m0 + wm * (BM / 2) + i * 16 + q * 4 + r;
#pragma unroll
        for (int j = 0; j < TN; j++) {
          const int gc = (int)n0 + wn * (BN / 2) + j * 16 + l16;
          atomicAdd(&a.Cf[gr * 1024 + gc], acc[i][j][r]);
        }
      }
    }
  } else if constexpr (EPI == 2) {
#pragma unroll
    for (int i = 0; i < TM; i++) {
#pragma unroll
      for (int r = 0; r < 4; r++) {
        const long gr = m0 + wm * (BM / 2) + i * 16 + q * 4 + r;
#pragma unroll
        for (int j = 0; j < TN; j++) {
          const int gc = (int)n0 + wn * (BN / 2) + j * 16 + l16;
          a.Ch[gr * 1024 + gc] = (f16)tanhf(acc[i][j][r] + a.bias[gc]);
        }
      }
    }
  } else if constexpr (EPI == 3) {
    float wave_ss = 0.f;
#pragma unroll
    for (int i = 0; i < TM; i++) {
#pragma unroll
      for (int r = 0; r < 4; r++) {
        const long gr = m0 + wm * (BM / 2) + i * 16 + q * 4 + r;
        float ss = 0.f;
#pragma unroll
        for (int j = 0; j < TN; j++) {
          const int gc = (int)n0 + wn * (BN / 2) + j * 16 + l16;
          const long ix = gr * 1024 + gc;
          const float v = (a.op[ix] - a.om[ix]) + acc[i][j][r] + a.bias[gc];
          a.Ch[ix] = (f16)v;
          ss += v * v;
        }
        ss += __shfl_xor(ss, 1); ss += __shfl_xor(ss, 2);
        ss += __shfl_xor(ss, 4); ss += __shfl_xor(ss, 8);
        if (l16 == 0) {
          atomicAdd(a.pt_out + gr, ss);
          wave_ss += ss;
        }
      }
    }
    wave_ss += __shfl_xor(wave_ss, 16);
    wave_ss += __shfl_xor(wave_ss, 32);
    if (lane == 0) atomicAdd(a.tsum_out, wave_ss);
  } else if constexpr (EPI == 4) {
    const float tsc = a.ts[0];
#pragma unroll
    for (int i = 0; i < TM; i++) {
#pragma unroll
      for (int r = 0; r < 4; r++) {
        const long gr = m0 + wm * (BM / 2) + i * 16 + q * 4 + r;
        const float sq = sqrtf(a.pt[gr] + 1e-8f) * tsc;
#pragma unroll
        for (int j = 0; j < TN; j++) {
          const int gc = (int)n0 + wn * (BN / 2) + j * 16 + l16;
          const long ix = gr * 1024 + gc;
          const float v = tanhf(acc[i][j][r] + a.bias[gc]);
          a.Cf[ix] = 0.5f * (a.op[ix] + a.om[ix]) + sq * v;
        }
      }
    }
  } else if constexpr (EPI == 5) {
    const float* bias = a.bias + (long)z * a.zbias;
    f16* C = a.Ch + (long)z * a.zC;
#pragma unroll
    for (int i = 0; i < TM; i++) {
#pragma unroll
      for (int r = 0; r < 4; r++) {
        const long grl = m0 + wm * (BM / 2) + i * 16 + q * 4 + r;
        if (grl < cn) {
          const float wv = Lg[grl - m0];
#pragma unroll
          for (int j = 0; j < TN; j++) {
            const int gc = (int)n0 + wn * (BN / 2) + j * 16 + l16;
            float v = acc[i][j][r] + bias[gc];
            v = fmaxf(v, 0.f) * wv;
            C[grl * a.ldc + gc] = (f16)v;
          }
        }
      }
    }
  } else {  // EPI == 6: routed scatter
#pragma unroll
    for (int i = 0; i < TM; i++) {
#pragma unroll
      for (int r = 0; r < 4; r++) {
        const long grl = m0 + wm * (BM / 2) + i * 16 + q * 4 + r;
        if (grl < cn) {
          const long row = a.rows[z * 2048 + grl];
#pragma unroll
          for (int j = 0; j < TN; j++) {
            const int gc = (int)n0 + wn * (BN / 2) + j * 16 + l16;
            atomicAdd(&a.Cf[row * 1024 + gc], acc[i][j][r]);
          }
        }
      }
    }
  }
}

// ---------------------------------------------------------------- launcher

extern "C" void kernel_launch(void* const* d_in, const int* in_sizes, int n_in,
                              void* d_out, int out_size, void* d_ws, size_t ws_size,
                              hipStream_t stream) {
  (void)in_sizes; (void)n_in; (void)out_size; (void)ws_size;
  const float* x    = (const float*)d_in[0];
  const float* gaw  = (const float*)d_in[1];
  const float* gab  = (const float*)d_in[2];
  const float* wa1  = (const float*)d_in[3];
  const float* ba1  = (const float*)d_in[4];
  const float* wa2  = (const float*)d_in[5];
  const float* ba2  = (const float*)d_in[6];
  const float* ggw  = (const float*)d_in[7];
  const float* ggb  = (const float*)d_in[8];
  const float* wg1  = (const float*)d_in[9];
  const float* bg1  = (const float*)d_in[10];
  const float* wg2  = (const float*)d_in[11];
  const float* bg2  = (const float*)d_in[12];
  const float* smw1 = (const float*)d_in[13];
  const float* smb1 = (const float*)d_in[14];
  const float* smw2 = (const float*)d_in[15];
  const float* smb2 = (const float*)d_in[16];
  const float* siw  = (const float*)d_in[17];
  const float* sib  = (const float*)d_in[18];
  const float* ftw  = (const float*)d_in[19];
  const float* ftb  = (const float*)d_in[20];
  const float* tsc  = (const float*)d_in[21];
  // d_in[22] = n_steps (==3, hard-coded)

  char* p = (char*)d_ws;
  size_t off = 0;
  auto alloc = [&](size_t bytes) -> char* {
    char* r = p + off;
    off = (off + bytes + 255) & ~(size_t)255;
    return r;
  };
  f16* xb     = (f16*)alloc(2048UL * 1024 * 2);
  f16* w1t    = (f16*)alloc(18UL * 2048 * 1024 * 2);  // wa1t(12)+wg1t(6); later wa2t+wg2t
  f16* smw2t  = (f16*)alloc(1024UL * 2048 * 2);
  f16* sit    = (f16*)alloc(1024UL * 1024 * 2);
  f16* ftt    = (f16*)alloc(1024UL * 1024 * 2);
  f16* hA     = (f16*)alloc(12UL * 2048 * 2048 * 2);  // compact per-expert rows
  f16* hG     = (f16*)alloc(2048UL * 12288 * 2);
  float* outP = (float*)alloc(2048UL * 1024 * 4);
  float* outM = (float*)alloc(2048UL * 1024 * 4);
  f16* hsmb   = (f16*)alloc(2048UL * 2048 * 2);
  f16* sst    = (f16*)alloc(2048UL * 1024 * 2);
  f16* modb   = (f16*)alloc(2048UL * 1024 * 2);
  float* wAb  = (float*)alloc(2048 * 12 * 4);
  float* wGb  = (float*)alloc(2048 * 6 * 4);
  float* entb = (float*)alloc(2048 * 4);
  float* ptb  = (float*)alloc(4 * 2048 * 4);          // 32768 B
  float* tsb  = (float*)alloc(4 * 4);                 // at ptb+32768
  int*   cntb = (int*)alloc(12 * 4);                  // at ptb+33024
  int*   rowsb = (int*)alloc(12 * 2048 * 4);
  float* gvalb = (float*)alloc(12 * 2048 * 4);

  f16* wa1t = w1t;
  f16* wg1t = w1t + 12UL * 2048 * 1024;
  f16* wa2t = w1t;                       // per-expert [1024][2048], reused AFTER GEMM1
  f16* wg2t = w1t + 12UL * 1024 * 2048;  // flat [1024][12288]

  // zero: ptb(32768) + pad tsb(256) + cnt(48) ; and split-K accumulators
  hipMemsetAsync(ptb, 0, 33072, stream);
  hipMemsetAsync(outP, 0, 2 * 2048UL * 1024 * 4, stream);  // outP+outM contiguous

  // weight conversion + transpose to [N][K] fp16
  transpose_cast<<<dim3(64, 32, 12), 256, 0, stream>>>(wa1, wa1t, 1024, 2048,
      1024L * 2048, 2048L * 1024, 1024);
  transpose_cast<<<dim3(64, 32, 6), 256, 0, stream>>>(wg1, wg1t, 1024, 2048,
      1024L * 2048, 2048L * 1024, 1024);
  transpose_cast<<<dim3(32, 64, 1), 256, 0, stream>>>(smw2, smw2t, 2048, 1024, 0, 0, 2048);
  transpose_cast<<<dim3(32, 32, 1), 256, 0, stream>>>(siw, sit, 1024, 1024, 0, 0, 1024);
  transpose_cast<<<dim3(32, 32, 1), 256, 0, stream>>>(ftw, ftt, 1024, 1024, 0, 0, 1024);
  castx_kernel<<<2048, 256, 0, stream>>>(x, xb);
  gating_kernel<<<2048, 256, 0, stream>>>(x, gaw, gab, ggw, ggb, wAb, wGb, entb,
                                          rowsb, gvalb, cntb);

  // GEMM1-A routed: hA[e][ri] = w * relu(x[rows[e][ri]] @ w1[e] + b1[e])
  GA g{};
  g.A = xb; g.lda = 1024; g.zA = 0;
  g.B = wa1t; g.ldb = 1024; g.zB = 2048L * 1024; g.nk = 32;
  g.Ch = hA; g.ldc = 2048; g.zC = 2048L * 2048; g.bias = ba1; g.zbias = 2048;
  g.rows = rowsb; g.gval = gvalb; g.cnt = cntb;
  gemm<128, 128, 5, 3><<<3072, 256, 0, stream>>>(g);
  // GEMM1-G dense: hG (flat, gate folded)
  GA g1{};
  g1.A = xb; g1.lda = 1024; g1.zA = 0;
  g1.B = wg1t; g1.ldb = 1024; g1.zB = 2048L * 1024; g1.nk = 32;
  g1.Ch = hG; g1.ldc = 12288; g1.zC = 2048; g1.bias = bg1; g1.zbias = 2048;
  g1.w = wGb; g1.ws = 6;
  gemm<128, 128, 0, 1><<<1536, 256, 0, stream>>>(g1);

  // now wa1t/wg1t are dead: convert second-layer weights into the same region
  transpose_cast<<<dim3(32, 64, 12), 256, 0, stream>>>(wa2, wa2t, 2048, 1024,
      2048L * 1024, 1024L * 2048, 2048);   // per-expert [1024][2048]
  transpose_cast<<<dim3(32, 64, 6), 256, 0, stream>>>(wg2, wg2t, 2048, 1024,
      2048L * 1024, 2048, 12288);          // flat [1024][12288]

  // GEMM2-A routed: out_plus[rows[e][ri]] += hA[e][ri] @ wa2[e]^T
  GA g2{};
  g2.A = hA; g2.lda = 2048; g2.zA = 2048L * 2048;
  g2.B = wa2t; g2.ldb = 2048; g2.zB = 1024L * 2048; g2.nk = 64;
  g2.Cf = outP;
  g2.rows = rowsb; g2.cnt = cntb;
  gemm<128, 128, 6, 4><<<1536, 256, 0, stream>>>(g2);
  // GEMM2-G: flat K=12288, split-K=8, atomic accumulate
  GA g2g{};
  g2g.A = hG; g2g.lda = 12288; g2g.zA = 1536;
  g2g.B = wg2t; g2g.ldb = 12288; g2g.zB = 1536; g2g.nk = 48;
  g2g.Cf = outM;
  gemm<128, 128, 1, 2><<<1024, 256, 0, stream>>>(g2g);

  tension0_kernel<<<2048, 256, 0, stream>>>(outP, outM, wAb, wGb, ba2, bg2, ptb, tsb);

  for (int s = 0; s < 3; s++) {
    hsm_kernel<<<dim3(8, 32), 256, 0, stream>>>(ptb + s * 2048, tsb + s, smw1, smb1, hsmb, s);
    GA g3{};
    g3.A = hsmb; g3.lda = 2048; g3.zA = 0;
    g3.B = smw2t; g3.ldb = 2048; g3.zB = 0; g3.nk = 64;
    g3.Ch = sst; g3.ldc = 1024; g3.bias = smb2;
    gemm<64, 64, 2, 0><<<dim3(16, 32, 1), 256, 0, stream>>>(g3);
    GA g4{};
    g4.A = sst; g4.lda = 1024; g4.zA = 0;
    g4.B = sit; g4.ldb = 1024; g4.zB = 0; g4.nk = 32;
    g4.Ch = modb; g4.ldc = 1024; g4.bias = sib; g4.op = outP; g4.om = outM;
    g4.pt_out = ptb + (s + 1) * 2048; g4.tsum_out = tsb + (s + 1);
    gemm<64, 64, 3, 0><<<dim3(16, 32, 1), 256, 0, stream>>>(g4);
  }

  GA g5{};
  g5.A = modb; g5.lda = 1024; g5.zA = 0;
  g5.B = ftt; g5.ldb = 1024; g5.zB = 0; g5.nk = 32;
  g5.Cf = (float*)d_out; g5.ldc = 1024; g5.bias = ftb; g5.op = outP; g5.om = outM;
  g5.pt = ptb + 3 * 2048; g5.ts = tsc;
  gemm<64, 64, 4, 0><<<dim3(16, 32, 1), 256, 0, stream>>>(g5);

  aux_kernel<<<1, 256, 0, stream>>>(entb, tsb, (float*)d_out + 2048UL * 1024);
}

// Round 4
// 1079.860 us; speedup vs baseline: 1.8368x; 1.1267x over previous
//
#include <hip/hip_runtime.h>

typedef _Float16 f16;
typedef f16  f16x8 __attribute__((ext_vector_type(8)));
typedef f16  f16x4 __attribute__((ext_vector_type(4)));
typedef float f32x4 __attribute__((ext_vector_type(4)));

#define LOAD_LDS16(gp, lp) __builtin_amdgcn_global_load_lds( \
    (const __attribute__((address_space(1))) void*)(gp),     \
    (__attribute__((address_space(3))) void*)(lp), 16, 0, 0)

// ---------------------------------------------------------------- helpers

__global__ __launch_bounds__(256) void castx_kernel(const float* __restrict__ x,
                                                    f16* __restrict__ o) {
  long i = ((long)blockIdx.x * 256 + threadIdx.x) * 4;
  const float4 v = *(const float4*)(x + i);
  f16x4 h; h.x = (f16)v.x; h.y = (f16)v.y; h.z = (f16)v.z; h.w = (f16)v.w;
  *(f16x4*)(o + i) = h;
}

// src [z][R][C] fp32  ->  dst (+z*dbatch) [c][r] fp16 with row stride dld
__global__ __launch_bounds__(256) void transpose_cast(const float* __restrict__ src,
                                                      f16* __restrict__ dst,
                                                      int R, int C, long sbatch,
                                                      long dbatch, int dld) {
  __shared__ float tile[32][33];
  const int zc = blockIdx.x * 32;
  const int zr = blockIdx.y * 32;
  const int z  = blockIdx.z;
  const float* s = src + (long)z * sbatch;
  f16* d = dst + (long)z * dbatch;
  const int tx = threadIdx.x & 31, ty = threadIdx.x >> 5;
#pragma unroll
  for (int rr = 0; rr < 32; rr += 8)
    tile[ty + rr][tx] = s[(long)(zr + ty + rr) * C + (zc + tx)];
  __syncthreads();
#pragma unroll
  for (int rr = 0; rr < 32; rr += 8)
    d[(long)(zc + ty + rr) * dld + (zr + tx)] = (f16)tile[tx][ty + rr];
}

// gating: logits, top-4-of-12 (lists + per-row slot map), softmax(6)+entropy.
__global__ __launch_bounds__(256) void gating_kernel(
    const float* __restrict__ x, const float* __restrict__ gaw,
    const float* __restrict__ gab, const float* __restrict__ ggw,
    const float* __restrict__ ggb,
    float* __restrict__ wG, float* __restrict__ ent,
    int* __restrict__ rows, float* __restrict__ gval, int* __restrict__ cnt,
    int* __restrict__ eA, int* __restrict__ posA, float* __restrict__ wA4) {
  const int b = blockIdx.x, t = threadIdx.x;
  const float* xr = x + (long)b * 1024;
  float pa[12], pg[6];
#pragma unroll
  for (int e = 0; e < 12; e++) pa[e] = 0.f;
#pragma unroll
  for (int e = 0; e < 6; e++) pg[e] = 0.f;
  const int i0 = t * 4;
  const float4 xv = *(const float4*)(xr + i0);
  const float xs[4] = {xv.x, xv.y, xv.z, xv.w};
#pragma unroll
  for (int u = 0; u < 4; u++) {
    const float xi = xs[u];
    const float* ga = gaw + (long)(i0 + u) * 12;
    const float* gg = ggw + (long)(i0 + u) * 6;
#pragma unroll
    for (int e = 0; e < 12; e++) pa[e] += xi * ga[e];
#pragma unroll
    for (int e = 0; e < 6; e++) pg[e] += xi * gg[e];
  }
#pragma unroll
  for (int e = 0; e < 12; e++)
    for (int m = 1; m < 64; m <<= 1) pa[e] += __shfl_xor(pa[e], m);
#pragma unroll
  for (int e = 0; e < 6; e++)
    for (int m = 1; m < 64; m <<= 1) pg[e] += __shfl_xor(pg[e], m);
  __shared__ float rw[4][18];
  const int lane = t & 63, wv = t >> 6;
  if (lane == 0) {
#pragma unroll
    for (int e = 0; e < 12; e++) rw[wv][e] = pa[e];
#pragma unroll
    for (int e = 0; e < 6; e++) rw[wv][12 + e] = pg[e];
  }
  __syncthreads();
  if (t == 0) {
    float la[12], lg[6];
#pragma unroll
    for (int e = 0; e < 12; e++)
      la[e] = rw[0][e] + rw[1][e] + rw[2][e] + rw[3][e] + gab[e];
#pragma unroll
    for (int e = 0; e < 6; e++)
      lg[e] = rw[0][12 + e] + rw[1][12 + e] + rw[2][12 + e] + rw[3][12 + e] + ggb[e];
    unsigned used = 0; float tv[4]; int tix[4];
    for (int k = 0; k < 4; k++) {
      float best = -3.4e38f; int bi = 0;
      for (int e = 0; e < 12; e++)
        if (!((used >> e) & 1u) && la[e] > best) { best = la[e]; bi = e; }
      tv[k] = best; tix[k] = bi; used |= 1u << bi;
    }
    const float mx = tv[0];
    float s = 0.f, w4[4];
    for (int k = 0; k < 4; k++) { w4[k] = expf(tv[k] - mx); s += w4[k]; }
    for (int k = 0; k < 4; k++) {
      const float w = w4[k] / s;
      const int e = tix[k];
      const int pos = atomicAdd(&cnt[e], 1);
      rows[e * 2048 + pos] = b;
      gval[e * 2048 + pos] = w;
      eA[b * 4 + k] = e;
      posA[b * 4 + k] = pos;
      wA4[b * 4 + k] = w;
    }
    float mg = lg[0];
    for (int e = 1; e < 6; e++) mg = fmaxf(mg, lg[e]);
    float sg = 0.f, wg6[6];
    for (int e = 0; e < 6; e++) { wg6[e] = expf(lg[e] - mg); sg += wg6[e]; }
    float H = 0.f;
    for (int e = 0; e < 6; e++) {
      const float w = wg6[e] / sg;
      wG[b * 6 + e] = w;
      H -= w * logf(w + 1e-8f);
    }
    ent[b] = H;
  }
}

__global__ void base_kernel(const int* __restrict__ cnt, int* __restrict__ baseA) {
  if (threadIdx.x == 0 && blockIdx.x == 0) {
    int r = 0;
    for (int e = 0; e < 12; e++) { baseA[e] = r; r += cnt[e]; }
  }
}

// combine: out_plus/out_minus from compact res + gate-weighted biases; tension0
__global__ __launch_bounds__(256) void combine_kernel(
    const f16* __restrict__ res, const int* __restrict__ eA,
    const int* __restrict__ posA, const float* __restrict__ wA4,
    const float* __restrict__ wG, const int* __restrict__ baseA,
    const float* __restrict__ ba2, const float* __restrict__ bg2,
    float* __restrict__ outP, float* __restrict__ outM,
    float* __restrict__ pt0, float* __restrict__ ts0) {
  const long b = blockIdx.x;
  const int t = threadIdx.x;
  const int c = t * 4;
  float4 P = {0.f, 0.f, 0.f, 0.f}, M = {0.f, 0.f, 0.f, 0.f};
#pragma unroll
  for (int k = 0; k < 4; k++) {
    const int e = eA[b * 4 + k];
    const long slot = baseA[e] + posA[b * 4 + k];
    const f16x4 v = *(const f16x4*)(res + slot * 1024 + c);
    const float w = wA4[b * 4 + k];
    const float4 bb = *(const float4*)(ba2 + (long)e * 1024 + c);
    P.x += (float)v.x + w * bb.x; P.y += (float)v.y + w * bb.y;
    P.z += (float)v.z + w * bb.z; P.w += (float)v.w + w * bb.w;
  }
#pragma unroll
  for (int e = 0; e < 6; e++) {
    const f16x4 v = *(const f16x4*)(res + (8192L + e * 2048 + b) * 1024 + c);
    const float w = wG[b * 6 + e];
    const float4 bb = *(const float4*)(bg2 + (long)e * 1024 + c);
    M.x += (float)v.x + w * bb.x; M.y += (float)v.y + w * bb.y;
    M.z += (float)v.z + w * bb.z; M.w += (float)v.w + w * bb.w;
  }
  *(float4*)(outP + b * 1024 + c) = P;
  *(float4*)(outM + b * 1024 + c) = M;
  const float dx = P.x - M.x, dy = P.y - M.y, dz = P.z - M.z, dw = P.w - M.w;
  float s = dx * dx + dy * dy + dz * dz + dw * dw;
#pragma unroll
  for (int m = 1; m < 64; m <<= 1) s += __shfl_xor(s, m);
  __shared__ float rw[4];
  if ((t & 63) == 0) rw[t >> 6] = s;
  __syncthreads();
  if (t == 0) {
    const float tot = rw[0] + rw[1] + rw[2] + rw[3];
    pt0[b] = tot;
    atomicAdd(ts0, tot);
  }
}

__global__ __launch_bounds__(256) void hsm_kernel(
    const float* __restrict__ pt, const float* __restrict__ tsum,
    const float* __restrict__ w1, const float* __restrict__ b1,
    f16* __restrict__ o, int step) {
  const int j = blockIdx.x * 256 + threadIdx.x;
  const int b0 = blockIdx.y * 64;
  const float u0 = w1[j], u1 = w1[2048 + j], u2 = w1[4096 + j], bb = b1[j];
  const float tm = tsum[0] * (1.f / 2048.f);
  const float st = (float)step * (1.f / 3.f);
#pragma unroll 4
  for (int r = 0; r < 64; r++) {
    const int b = b0 + r;
    const float t = pt[b];
    const float delta = (step == 0) ? 0.f : (t - tm);
    o[(long)b * 2048 + j] = (f16)tanhf(t * u0 + delta * u1 + st * u2 + bb);
  }
}

__global__ __launch_bounds__(256) void aux_kernel(const float* __restrict__ ent,
                                                  const float* __restrict__ tsum,
                                                  float* __restrict__ out) {
  const int t = threadIdx.x;
  float s = 0.f;
  for (int i = t; i < 2048; i += 256) s += ent[i];
#pragma unroll
  for (int m = 1; m < 64; m <<= 1) s += __shfl_xor(s, m);
  __shared__ float rw[4];
  if ((t & 63) == 0) rw[t >> 6] = s;
  __syncthreads();
  if (t == 0) {
    const float h = (rw[0] + rw[1] + rw[2] + rw[3]) * (1.f / 2048.f);
    const float d = h - 1.0114042647f;
    const float el = d * d;
    const float t0 = tsum[0] * (1.f / 2048.f), t1 = tsum[1] * (1.f / 2048.f);
    const float t2 = tsum[2] * (1.f / 2048.f), t3 = tsum[3] * (1.f / 2048.f);
    const float conv = (fabsf(t1 - t0) + fabsf(t2 - t1) + fabsf(t3 - t2)) * (1.f / 3.f);
    out[0] = el + 0.001f * conv;
  }
}

// ------------------------------------------------ unified GEMM1 (18 experts)
// h[row] = gate * relu(x[src_row] @ w1t[e18]^T + b1[e18]);  BM=128 BN=128 K=1024
// grid 4608: ids 0..3071 EngineA routed, 3072..4607 EngineG dense.
__global__ __launch_bounds__(256) void gemm1_kernel(
    const f16* __restrict__ x, const f16* __restrict__ w1t,
    const float* __restrict__ ba1, const float* __restrict__ bg1,
    f16* __restrict__ h, const int* __restrict__ rows,
    const float* __restrict__ gval, const int* __restrict__ cnt,
    const int* __restrict__ baseA, const float* __restrict__ wG) {
  __shared__ f16 Al[2][128 * 32];
  __shared__ f16 Bl[2][128 * 32];
  __shared__ int   Lrow[128];
  __shared__ float Lg[128];
  int id = blockIdx.x;
  int e18, mi, ni, live; long row0; const float* bp;
  if (id < 3072) {                       // EngineA routed (XCD owns (e,n), m fast)
    const int k = id & 7, t = id >> 3;
    mi = t & 15; const int pid = k * 24 + (t >> 4);
    const int e = pid >> 4; ni = pid & 15;
    live = cnt[e] - mi * 128;
    if (live <= 0) return;
    if (live > 128) live = 128;
    row0 = baseA[e] + mi * 128; e18 = e; bp = ba1 + (long)e * 2048;
  } else {
    id -= 3072;
    const int k = id & 7, t = id >> 3;
    mi = t & 15; const int pid = k * 12 + (t >> 4);
    const int e = pid >> 4; ni = pid & 15;
    row0 = 8192L + e * 2048 + mi * 128; live = 128;
    e18 = 12 + e; bp = bg1 + (long)e * 2048;
  }
  const int tid = threadIdx.x;
  const bool routed = (e18 < 12);
  if (tid < 128) {
    const int gi = mi * 128 + tid;
    if (routed) {
      const bool ok = tid < live;
      Lrow[tid] = ok ? rows[e18 * 2048 + gi] : 0;
      Lg[tid]   = ok ? gval[e18 * 2048 + gi] : 0.f;
    } else {
      Lrow[tid] = gi;
      Lg[tid] = wG[gi * 6 + (e18 - 12)];
    }
  }
  __syncthreads();
  const int r0 = Lrow[tid >> 2], r1 = Lrow[64 + (tid >> 2)];
  const f16* a0 = x + (long)r0 * 1024 + (tid & 3) * 8;
  const f16* a1 = x + (long)r1 * 1024 + (tid & 3) * 8;
  const f16* b0 = w1t + (long)e18 * 2048 * 1024 + ((long)ni * 128 + (tid >> 2)) * 1024 + (tid & 3) * 8;
  const f16* b1p = b0 + 64 * 1024;

  const int wave = tid >> 6, lane = tid & 63;
  const int wm = wave & 1, wn = wave >> 1;
  const int l16 = lane & 15, q = lane >> 4;
  f32x4 acc[4][4] = {};

  LOAD_LDS16(a0, &Al[0][tid * 8]);
  LOAD_LDS16(a1, &Al[0][(256 + tid) * 8]);
  LOAD_LDS16(b0, &Bl[0][tid * 8]);
  LOAD_LDS16(b1p, &Bl[0][(256 + tid) * 8]);
  for (int kk = 0; kk < 32; ++kk) {
    __syncthreads();
    const int cur = kk & 1;
    if (kk + 1 < 32) {
      const long k0 = (long)(kk + 1) * 32;
      const int nb = cur ^ 1;
      LOAD_LDS16(a0 + k0, &Al[nb][tid * 8]);
      LOAD_LDS16(a1 + k0, &Al[nb][(256 + tid) * 8]);
      LOAD_LDS16(b0 + k0, &Bl[nb][tid * 8]);
      LOAD_LDS16(b1p + k0, &Bl[nb][(256 + tid) * 8]);
    }
    f16x8 av[4], bv[4];
#pragma unroll
    for (int i = 0; i < 4; i++)
      av[i] = *(const f16x8*)&Al[cur][(wm * 64 + i * 16 + l16) * 32 + q * 8];
#pragma unroll
    for (int j = 0; j < 4; j++)
      bv[j] = *(const f16x8*)&Bl[cur][(wn * 64 + j * 16 + l16) * 32 + q * 8];
#pragma unroll
    for (int i = 0; i < 4; i++)
#pragma unroll
      for (int j = 0; j < 4; j++)
        acc[i][j] = __builtin_amdgcn_mfma_f32_16x16x32_f16(av[i], bv[j], acc[i][j], 0, 0, 0);
  }
  // epilogue: relu + gate, store h (row stride 2048)
#pragma unroll
  for (int i = 0; i < 4; i++) {
#pragma unroll
    for (int r = 0; r < 4; r++) {
      const int lr = wm * 64 + i * 16 + q * 4 + r;
      if (lr < live) {
        const float wv = Lg[lr];
        f16* C = h + (row0 + lr) * 2048;
#pragma unroll
        for (int j = 0; j < 4; j++) {
          const int gc = ni * 128 + wn * 64 + j * 16 + l16;
          const float v = fmaxf(acc[i][j][r] + bp[gc], 0.f) * wv;
          C[gc] = (f16)v;
        }
      }
    }
  }
}

// ------------------------------------------------ unified GEMM2 (18 experts)
// res[row] = h[row] @ w2t[e18]^T ; BM=128 BN=64 K=2048, plain f16 store
__global__ __launch_bounds__(256) void gemm2_kernel(
    const f16* __restrict__ h, const f16* __restrict__ w2t,
    f16* __restrict__ res, const int* __restrict__ cnt,
    const int* __restrict__ baseA) {
  __shared__ f16 Al[2][128 * 32];
  __shared__ f16 Bl[2][64 * 32];
  int id = blockIdx.x;
  int e18, mi, ni, live; long row0;
  if (id < 3072) {
    const int k = id & 7, t = id >> 3;
    mi = t & 15; const int pid = k * 24 + (t >> 4);
    const int e = pid >> 4; ni = pid & 15;
    live = cnt[e] - mi * 128;
    if (live <= 0) return;
    if (live > 128) live = 128;
    row0 = baseA[e] + mi * 128; e18 = e;
  } else {
    id -= 3072;
    const int k = id & 7, t = id >> 3;
    mi = t & 15; const int pid = k * 12 + (t >> 4);
    const int e = pid >> 4; ni = pid & 15;
    row0 = 8192L + e * 2048 + mi * 128; live = 128; e18 = 12 + e;
  }
  const int tid = threadIdx.x;
  const f16* a0 = h + (row0 + (tid >> 2)) * 2048 + (tid & 3) * 8;
  const f16* a1 = a0 + 64 * 2048;
  const f16* b0 = w2t + (long)e18 * 1024 * 2048 + ((long)ni * 64 + (tid >> 2)) * 2048 + (tid & 3) * 8;

  const int wave = tid >> 6, lane = tid & 63;
  const int wm = wave & 1, wn = wave >> 1;
  const int l16 = lane & 15, q = lane >> 4;
  f32x4 acc[4][2] = {};

  LOAD_LDS16(a0, &Al[0][tid * 8]);
  LOAD_LDS16(a1, &Al[0][(256 + tid) * 8]);
  LOAD_LDS16(b0, &Bl[0][tid * 8]);
  for (int kk = 0; kk < 64; ++kk) {
    __syncthreads();
    const int cur = kk & 1;
    if (kk + 1 < 64) {
      const long k0 = (long)(kk + 1) * 32;
      const int nb = cur ^ 1;
      LOAD_LDS16(a0 + k0, &Al[nb][tid * 8]);
      LOAD_LDS16(a1 + k0, &Al[nb][(256 + tid) * 8]);
      LOAD_LDS16(b0 + k0, &Bl[nb][tid * 8]);
    }
    f16x8 av[4], bv[2];
#pragma unroll
    for (int i = 0; i < 4; i++)
      av[i] = *(const f16x8*)&Al[cur][(wm * 64 + i * 16 + l16) * 32 + q * 8];
#pragma unroll
    for (int j = 0; j < 2; j++)
      bv[j] = *(const f16x8*)&Bl[cur][(wn * 32 + j * 16 + l16) * 32 + q * 8];
#pragma unroll
    for (int i = 0; i < 4; i++)
#pragma unroll
      for (int j = 0; j < 2; j++)
        acc[i][j] = __builtin_amdgcn_mfma_f32_16x16x32_f16(av[i], bv[j], acc[i][j], 0, 0, 0);
  }
#pragma unroll
  for (int i = 0; i < 4; i++) {
#pragma unroll
    for (int r = 0; r < 4; r++) {
      const int lr = wm * 64 + i * 16 + q * 4 + r;
      if (lr < live) {
        f16* C = res + (row0 + lr) * 1024 + ni * 64;
#pragma unroll
        for (int j = 0; j < 2; j++) {
          const int gc = wn * 32 + j * 16 + l16;
          C[gc] = (f16)acc[i][j][r];
        }
      }
    }
  }
}

// ------------------------------------------------ small dense GEMM (dbuf)

struct GA {
  const f16* A; long lda;
  const f16* B; long ldb;
  int nk;
  float* Cf; f16* Ch;
  const float* bias;
  const float* op; const float* om;
  const float* pt; const float* ts;
  float* pt_out; float* tsum_out;
};

// BM=BN=64. EPI: 2 tanh->f16 ; 3 mod+tension ; 4 final output
template <int EPI>
__global__ __launch_bounds__(256) void gemm_s(GA a) {
  __shared__ f16 Al[2][64 * 32];
  __shared__ f16 Bl[2][64 * 32];
  const int tid = threadIdx.x;
  const int wave = tid >> 6, lane = tid & 63;
  const int wm = wave & 1, wn = wave >> 1;
  const int l16 = lane & 15, q = lane >> 4;
  const long m0 = (long)blockIdx.y * 64;
  const long n0 = (long)blockIdx.x * 64;
  const f16* a0 = a.A + (m0 + (tid >> 2)) * a.lda + (tid & 3) * 8;
  const f16* b0 = a.B + (n0 + (tid >> 2)) * a.ldb + (tid & 3) * 8;
  f32x4 acc[2][2] = {};
  LOAD_LDS16(a0, &Al[0][tid * 8]);
  LOAD_LDS16(b0, &Bl[0][tid * 8]);
  for (int kk = 0; kk < a.nk; ++kk) {
    __syncthreads();
    const int cur = kk & 1;
    if (kk + 1 < a.nk) {
      const long k0 = (long)(kk + 1) * 32;
      const int nb = cur ^ 1;
      LOAD_LDS16(a0 + k0, &Al[nb][tid * 8]);
      LOAD_LDS16(b0 + k0, &Bl[nb][tid * 8]);
    }
    f16x8 av[2], bv[2];
#pragma unroll
    for (int i = 0; i < 2; i++)
      av[i] = *(const f16x8*)&Al[cur][(wm * 32 + i * 16 + l16) * 32 + q * 8];
#pragma unroll
    for (int j = 0; j < 2; j++)
      bv[j] = *(const f16x8*)&Bl[cur][(wn * 32 + j * 16 + l16) * 32 + q * 8];
#pragma unroll
    for (int i = 0; i < 2; i++)
#pragma unroll
      for (int j = 0; j < 2; j++)
        acc[i][j] = __builtin_amdgcn_mfma_f32_16x16x32_f16(av[i], bv[j], acc[i][j], 0, 0, 0);
  }
  if constexpr (EPI == 2) {
#pragma unroll
    for (int i = 0; i < 2; i++)
#pragma unroll
      for (int r = 0; r < 4; r++) {
        const long gr = m0 + wm * 32 + i * 16 + q * 4 + r;
#pragma unroll
        for (int j = 0; j < 2; j++) {
          const int gc = (int)n0 + wn * 32 + j * 16 + l16;
          a.Ch[gr * 1024 + gc] = (f16)tanhf(acc[i][j][r] + a.bias[gc]);
        }
      }
  } else if constexpr (EPI == 3) {
    float wave_ss = 0.f;
#pragma unroll
    for (int i = 0; i < 2; i++)
#pragma unroll
      for (int r = 0; r < 4; r++) {
        const long gr = m0 + wm * 32 + i * 16 + q * 4 + r;
        float ss = 0.f;
#pragma unroll
        for (int j = 0; j < 2; j++) {
          const int gc = (int)n0 + wn * 32 + j * 16 + l16;
          const long ix = gr * 1024 + gc;
          const float v = (a.op[ix] - a.om[ix]) + acc[i][j][r] + a.bias[gc];
          a.Ch[ix] = (f16)v;
          ss += v * v;
        }
        ss += __shfl_xor(ss, 1); ss += __shfl_xor(ss, 2);
        ss += __shfl_xor(ss, 4); ss += __shfl_xor(ss, 8);
        if (l16 == 0) {
          atomicAdd(a.pt_out + gr, ss);
          wave_ss += ss;
        }
      }
    wave_ss += __shfl_xor(wave_ss, 16);
    wave_ss += __shfl_xor(wave_ss, 32);
    if (lane == 0) atomicAdd(a.tsum_out, wave_ss);
  } else {  // EPI == 4
    const float tsc = a.ts[0];
#pragma unroll
    for (int i = 0; i < 2; i++)
#pragma unroll
      for (int r = 0; r < 4; r++) {
        const long gr = m0 + wm * 32 + i * 16 + q * 4 + r;
        const float sq = sqrtf(a.pt[gr] + 1e-8f) * tsc;
#pragma unroll
        for (int j = 0; j < 2; j++) {
          const int gc = (int)n0 + wn * 32 + j * 16 + l16;
          const long ix = gr * 1024 + gc;
          const float v = tanhf(acc[i][j][r] + a.bias[gc]);
          a.Cf[ix] = 0.5f * (a.op[ix] + a.om[ix]) + sq * v;
        }
      }
  }
}

// ---------------------------------------------------------------- launcher

extern "C" void kernel_launch(void* const* d_in, const int* in_sizes, int n_in,
                              void* d_out, int out_size, void* d_ws, size_t ws_size,
                              hipStream_t stream) {
  (void)in_sizes; (void)n_in; (void)out_size; (void)ws_size;
  const float* x    = (const float*)d_in[0];
  const float* gaw  = (const float*)d_in[1];
  const float* gab  = (const float*)d_in[2];
  const float* wa1  = (const float*)d_in[3];
  const float* ba1  = (const float*)d_in[4];
  const float* wa2  = (const float*)d_in[5];
  const float* ba2  = (const float*)d_in[6];
  const float* ggw  = (const float*)d_in[7];
  const float* ggb  = (const float*)d_in[8];
  const float* wg1  = (const float*)d_in[9];
  const float* bg1  = (const float*)d_in[10];
  const float* wg2  = (const float*)d_in[11];
  const float* bg2  = (const float*)d_in[12];
  const float* smw1 = (const float*)d_in[13];
  const float* smb1 = (const float*)d_in[14];
  const float* smw2 = (const float*)d_in[15];
  const float* smb2 = (const float*)d_in[16];
  const float* siw  = (const float*)d_in[17];
  const float* sib  = (const float*)d_in[18];
  const float* ftw  = (const float*)d_in[19];
  const float* ftb  = (const float*)d_in[20];
  const float* tsc  = (const float*)d_in[21];

  char* p = (char*)d_ws;
  size_t off = 0;
  auto alloc = [&](size_t bytes) -> char* {
    char* r = p + off;
    off = (off + bytes + 255) & ~(size_t)255;
    return r;
  };
  f16* xb     = (f16*)alloc(2048UL * 1024 * 2);
  f16* w1t    = (f16*)alloc(18UL * 2048 * 1024 * 2);   // later reused as w2t
  f16* smw2t  = (f16*)alloc(1024UL * 2048 * 2);
  f16* sit    = (f16*)alloc(1024UL * 1024 * 2);
  f16* ftt    = (f16*)alloc(1024UL * 1024 * 2);
  f16* h      = (f16*)alloc(20480UL * 2048 * 2);       // 8192 A-compact + 6*2048 G
  f16* res    = (f16*)alloc(20480UL * 1024 * 2);
  float* outP = (float*)alloc(2048UL * 1024 * 4);
  float* outM = (float*)alloc(2048UL * 1024 * 4);
  f16* hsmb   = (f16*)alloc(2048UL * 2048 * 2);
  f16* sst    = (f16*)alloc(2048UL * 1024 * 2);
  f16* modb   = (f16*)alloc(2048UL * 1024 * 2);
  float* entb = (float*)alloc(2048 * 4);
  float* wGb  = (float*)alloc(2048 * 6 * 4);
  float* ptb  = (float*)alloc(4 * 2048 * 4);           // 32768 B
  float* tsb  = (float*)alloc(4 * 4);                  // +32768 (rounds to 256)
  int*   cntb = (int*)alloc(12 * 4);                   // +33024
  int*   baseAb = (int*)alloc(12 * 4);
  int*   rowsb  = (int*)alloc(12 * 2048 * 4);
  float* gvalb  = (float*)alloc(12 * 2048 * 4);
  int*   eAb    = (int*)alloc(2048 * 4 * 4);
  int*   posAb  = (int*)alloc(2048 * 4 * 4);
  float* wA4b   = (float*)alloc(2048 * 4 * 4);

  f16* w2t = w1t;  // [18][1024][2048], reused after gemm1

  // zero tension accumulators + expert counters (contiguous region)
  hipMemsetAsync(ptb, 0, 33072, stream);

  // weight conversion + transpose to [N][K] fp16
  transpose_cast<<<dim3(64, 32, 12), 256, 0, stream>>>(wa1, w1t, 1024, 2048,
      1024L * 2048, 2048L * 1024, 1024);
  transpose_cast<<<dim3(64, 32, 6), 256, 0, stream>>>(wg1, w1t + 12UL * 2048 * 1024,
      1024, 2048, 1024L * 2048, 2048L * 1024, 1024);
  transpose_cast<<<dim3(32, 64, 1), 256, 0, stream>>>(smw2, smw2t, 2048, 1024, 0, 0, 2048);
  transpose_cast<<<dim3(32, 32, 1), 256, 0, stream>>>(siw, sit, 1024, 1024, 0, 0, 1024);
  transpose_cast<<<dim3(32, 32, 1), 256, 0, stream>>>(ftw, ftt, 1024, 1024, 0, 0, 1024);
  castx_kernel<<<2048, 256, 0, stream>>>(x, xb);
  gating_kernel<<<2048, 256, 0, stream>>>(x, gaw, gab, ggw, ggb, wGb, entb,
                                          rowsb, gvalb, cntb, eAb, posAb, wA4b);
  base_kernel<<<1, 64, 0, stream>>>(cntb, baseAb);

  // unified GEMM1 (A routed + G dense), one dispatch
  gemm1_kernel<<<4608, 256, 0, stream>>>(xb, w1t, ba1, bg1, h,
                                         rowsb, gvalb, cntb, baseAb, wGb);

  // layer-2 weights into the (now dead) w1t region
  transpose_cast<<<dim3(32, 64, 12), 256, 0, stream>>>(wa2, w2t, 2048, 1024,
      2048L * 1024, 1024L * 2048, 2048);
  transpose_cast<<<dim3(32, 64, 6), 256, 0, stream>>>(wg2, w2t + 12UL * 1024 * 2048,
      2048, 1024, 2048L * 1024, 1024L * 2048, 2048);

  // unified GEMM2, compact f16 out, no atomics
  gemm2_kernel<<<4608, 256, 0, stream>>>(h, w2t, res, cntb, baseAb);

  combine_kernel<<<2048, 256, 0, stream>>>(res, eAb, posAb, wA4b, wGb, baseAb,
                                           ba2, bg2, outP, outM, ptb, tsb);

  for (int s = 0; s < 3; s++) {
    hsm_kernel<<<dim3(8, 32), 256, 0, stream>>>(ptb + s * 2048, tsb + s, smw1, smb1, hsmb, s);
    GA g3{};
    g3.A = hsmb; g3.lda = 2048; g3.B = smw2t; g3.ldb = 2048; g3.nk = 64;
    g3.Ch = sst; g3.bias = smb2;
    gemm_s<2><<<dim3(16, 32), 256, 0, stream>>>(g3);
    GA g4{};
    g4.A = sst; g4.lda = 1024; g4.B = sit; g4.ldb = 1024; g4.nk = 32;
    g4.Ch = modb; g4.bias = sib; g4.op = outP; g4.om = outM;
    g4.pt_out = ptb + (s + 1) * 2048; g4.tsum_out = tsb + (s + 1);
    gemm_s<3><<<dim3(16, 32), 256, 0, stream>>>(g4);
  }

  GA g5{};
  g5.A = modb; g5.lda = 1024; g5.B = ftt; g5.ldb = 1024; g5.nk = 32;
  g5.Cf = (float*)d_out; g5.bias = ftb; g5.op = outP; g5.om = outM;
  g5.pt = ptb + 3 * 2048; g5.ts = tsc;
  gemm_s<4><<<dim3(16, 32), 256, 0, stream>>>(g5);

  aux_kernel<<<1, 256, 0, stream>>>(entb, tsb, (float*)d_out + 2048UL * 1024);
}